// Round 6
// baseline (1148.249 us; speedup 1.0000x reference)
//
#include <hip/hip_runtime.h>

// CKAFormer R13 (from R12; R12 post-mortem: 8-phase upd_k = 63.6us @ MfmaUtil
// 22% — WORSE than 2-barrier EPI1 (60us). Two root causes found by rederiving
// vs the R5-proven staging: (1) DOUBLE-SWIZZLE BUG — R5 stages the swizzled
// master VERBATIM (src col lgrp*8) and undoes at ds_read (^row&7); R12's STG
// inverse-swizzled at the SOURCE and kept the read XOR -> scrambled k-pairing
// for rows r&7!=c&7 (passed only because the gamma-term sits below the bf16
// noise floor). (2) vmcnt waits at p4/p8 drained stages issued 2-3 phases
// earlier (<900cyc HBM latency) -> stall every wait.
// R13 = within-run A/B on the update gemm:
// - rows 0..8191:    proven 2-barrier gemm_nt EPI1, grid (64,8).
// - rows 8192..16383: FIXED upd_k (verbatim staging src col grp*8; vmcnt(8)
//   waits at p2/p6/p8, steady in-flight 16 loads = 2 K-tiles margin; last-iter
//   p6/p8 drop to vmcnt(0) — all transitions race-checked), grid (32,4) with
//   offset pointers (8192 % 8 == 0 keeps all swizzles valid).
// Disjoint writes; both dispatches back-to-back -> per-kernel us directly
// comparable in one run. Everything else identical to R11/R12.

#define N_ROWS 16384
#define DIM 1024
#define HID 16
#define OUTD 64
#define DEPTH 6
#define GAMMA 1e-4f

typedef short bf16x8 __attribute__((ext_vector_type(8)));
typedef unsigned short u16x8 __attribute__((ext_vector_type(8)));
typedef float f32x4 __attribute__((ext_vector_type(4)));

#define AS1C(p) ((const __attribute__((address_space(1))) void*)(p))
#define AS3(p)  ((__attribute__((address_space(3))) void*)(p))

__device__ __forceinline__ unsigned short f2bf(float f) {
    unsigned u = __builtin_bit_cast(unsigned, f);
    u += 0x7fffu + ((u >> 16) & 1u);   // round-to-nearest-even
    return (unsigned short)(u >> 16);
}
__device__ __forceinline__ float b2f(ushort u) {
    unsigned x = ((unsigned)u) << 16;
    return __builtin_bit_cast(float, x);
}
// stored offset of logical element n within a swizzled row keyed by (row&7)
__device__ __forceinline__ int swz(int n, int row) {
    return (n & ~63) | ((((n >> 3) & 7) ^ (row & 7)) << 3) | (n & 7);
}

// ---------------------------------------------------------------------------
// Once per launch: master Xm = bf16(X) swizzled rows + ssout[row] = ||X[row]||^2.
__global__ __launch_bounds__(256) void tobf16_k(const float* __restrict__ X,
        ushort* __restrict__ Xm, float* __restrict__ ssout) {
    int row = blockIdx.x, t = threadIdx.x;
    float4 v = ((const float4*)(X + (size_t)row * DIM))[t];
    ushort4 o4;
    o4.x = f2bf(v.x); o4.y = f2bf(v.y); o4.z = f2bf(v.z); o4.w = f2bf(v.w);
    *(ushort4*)(Xm + (size_t)row * DIM + swz(t * 4, row)) = o4;
    float ss = v.x * v.x + v.y * v.y + v.z * v.z + v.w * v.w;
    for (int o = 32; o > 0; o >>= 1) ss += __shfl_down(ss, o);
    __shared__ float wsum[4];
    if ((t & 63) == 0) wsum[t >> 6] = ss;
    __syncthreads();
    if (t == 0) ssout[row] = wsum[0] + wsum[1] + wsum[2] + wsum[3];
}

// ---------------------------------------------------------------------------
// XnT[d][k] = bf16(Xm[k][d] / ||X[k]||), swizzled by d. LDS 64x65 f32 tile.
__device__ __forceinline__ void transpose_body(const ushort* __restrict__ Xm,
        const float* __restrict__ ss, ushort* __restrict__ XnT,
        int bx, int by, float* ts, float* riS) {
    int r0 = bx * 64;   // source row (k) tile
    int c0 = by * 64;   // source col (d) tile
    int t = threadIdx.x;
    if (t < 64) riS[t] = 1.0f / sqrtf(ss[r0 + t]);
    __syncthreads();
#pragma unroll
    for (int i = 0; i < 2; ++i) {
        int idx = i * 256 + t;
        int r = idx >> 3, lg = idx & 7;
        int rr = r0 + r;
        const ushort* p = Xm + (size_t)rr * DIM + c0 + ((lg ^ (rr & 7)) << 3);
        u16x8 a = *(const u16x8*)p;
        float s = riS[r];
        float* d = &ts[r * 65 + lg * 8];
#pragma unroll
        for (int u = 0; u < 8; ++u) d[u] = b2f(a[u]) * s;
    }
    __syncthreads();
#pragma unroll
    for (int i = 0; i < 2; ++i) {
        int g = i * 256 + t;
        int c = g >> 3;
        int rg = g & 7;
        u16x8 pk;
#pragma unroll
        for (int u = 0; u < 8; ++u) pk[u] = f2bf(ts[(rg * 8 + u) * 65 + c]);
        *(u16x8*)(XnT + (size_t)(c0 + c) * N_ROWS + r0 + ((rg ^ (c & 7)) << 3)) = pk;
    }
}

// ---------------------------------------------------------------------------
// z[m][h] = (Xm[m]·W1[:,h]) / ||X[m]|| + b1[h]   (ss=nullptr -> no scale; final).
__device__ __forceinline__ void zgemm_body(const ushort* __restrict__ Xm,
        const ushort* __restrict__ W1T, const float* __restrict__ b1,
        float* __restrict__ z, const float* __restrict__ ss, int bidx) {
    int t = threadIdx.x;
    int wave = t >> 6, lane = t & 63;
    int rl = lane & 15, q = lane >> 4;
    int rowbase = bidx * 64 + wave * 16;
    int m = rowbase + rl;
    int msw = m & 7;
    const ushort* arow = Xm + (size_t)m * DIM;
    const ushort* brow = W1T + (size_t)rl * DIM + q * 8;
    f32x4 acc = {0.f, 0.f, 0.f, 0.f};
#pragma unroll 8
    for (int kt = 0; kt < DIM; kt += 32) {
        int gl = ((kt >> 3) & 7) | q;
        int off = (kt & ~63) + ((gl ^ msw) << 3);
        bf16x8 a = *(const bf16x8*)(arow + off);
        bf16x8 b = *(const bf16x8*)(brow + kt);
        acc = __builtin_amdgcn_mfma_f32_16x16x32_bf16(a, b, acc, 0, 0, 0);
    }
#pragma unroll
    for (int rg = 0; rg < 4; ++rg) {
        int mm = rowbase + q * 4 + rg;
        float s = ss ? 1.0f / sqrtf(ss[mm]) : 1.0f;
        z[(size_t)mm * HID + rl] = acc[rg] * s + b1[rl];
    }
}

// ---------------------------------------------------------------------------
// Fused transpose (blocks 0..4095) + zgemm (blocks 4096..4351).
__global__ __launch_bounds__(256) void txz_k(const ushort* __restrict__ Xm,
        const float* __restrict__ ss, ushort* __restrict__ XnT,
        const ushort* __restrict__ W1T, const float* __restrict__ b1,
        float* __restrict__ z) {
    __shared__ float ts[64 * 65];
    __shared__ float riS[64];
    int bid = blockIdx.x;
    if (bid < 4096) transpose_body(Xm, ss, XnT, bid & 255, bid >> 8, ts, riS);
    else            zgemm_body(Xm, W1T, b1, z, ss, bid - 4096);
}

// standalone wrappers (small path / final)
__global__ __launch_bounds__(256) void transpose_k(const ushort* __restrict__ Xm,
        const float* __restrict__ ss, ushort* __restrict__ XnT) {
    __shared__ float ts[64 * 65];
    __shared__ float riS[64];
    transpose_body(Xm, ss, XnT, blockIdx.x, blockIdx.y, ts, riS);
}
__global__ __launch_bounds__(256) void zgemm_k(const ushort* __restrict__ Xm,
        const ushort* __restrict__ W1T, const float* __restrict__ b1,
        float* __restrict__ z, const float* __restrict__ ss) {
    zgemm_body(Xm, W1T, b1, z, ss, blockIdx.x);
}

// ---------------------------------------------------------------------------
__global__ __launch_bounds__(256) void prep_w1t_k(const float* __restrict__ W1,
        ushort* __restrict__ W1T) {
    int idx = blockIdx.x * 256 + threadIdx.x;   // 16384
    int h = idx >> 10, j = idx & 1023;
    W1T[idx] = f2bf(W1[j * HID + h]);
}

// ---------------------------------------------------------------------------
// Per row: h = relu(z); logits = h@W2 + b2; softmax -> Pb (swizzled by m&7)
// + PTb (rows o, swizzled by o&7), or (do_softmax=0) logits f32 to out.
__global__ __launch_bounds__(256) void head_k(const float* __restrict__ z,
        const float* __restrict__ W2, const float* __restrict__ b2,
        ushort* __restrict__ Pb, ushort* __restrict__ PTb,
        float* __restrict__ out, int do_softmax) {
    __shared__ float w2s[HID * OUTD];
    __shared__ float b2s[OUTD];
    int t = threadIdx.x;
    ((float4*)w2s)[t] = ((const float4*)W2)[t];
    if (t < OUTD) b2s[t] = b2[t];
    __syncthreads();
    int m = blockIdx.x * 256 + t;
    float h[HID];
    const float4* zp = (const float4*)(z + (size_t)m * HID);
#pragma unroll
    for (int i = 0; i < 4; ++i) {
        float4 v = zp[i];
        h[i * 4 + 0] = fmaxf(v.x, 0.f); h[i * 4 + 1] = fmaxf(v.y, 0.f);
        h[i * 4 + 2] = fmaxf(v.z, 0.f); h[i * 4 + 3] = fmaxf(v.w, 0.f);
    }
    float lo[OUTD];
#pragma unroll
    for (int o = 0; o < OUTD; ++o) lo[o] = b2s[o];
    for (int i = 0; i < HID; ++i) {
        float hv = h[i];
#pragma unroll
        for (int o = 0; o < OUTD; ++o) lo[o] += hv * w2s[i * OUTD + o];
    }
    if (do_softmax) {
        float mx = lo[0];
#pragma unroll
        for (int o = 1; o < OUTD; ++o) mx = fmaxf(mx, lo[o]);
        float sm = 0.f;
#pragma unroll
        for (int o = 0; o < OUTD; ++o) { float e = __expf(lo[o] - mx); lo[o] = e; sm += e; }
        float inv = 1.0f / sm;
#pragma unroll
        for (int o8 = 0; o8 < 8; ++o8) {
            u16x8 pk;
#pragma unroll
            for (int u = 0; u < 8; ++u) pk[u] = f2bf(lo[o8 * 8 + u] * inv);
            ((u16x8*)(Pb + (size_t)m * OUTD))[o8 ^ (m & 7)] = pk;
        }
#pragma unroll
        for (int o = 0; o < OUTD; ++o)
            PTb[(size_t)o * N_ROWS + swz(m, o)] = f2bf(lo[o] * inv);
    } else {
        float4* op = (float4*)(out + (size_t)m * OUTD);
#pragma unroll
        for (int o4 = 0; o4 < 16; ++o4) {
            float4 v; v.x = lo[o4 * 4 + 0]; v.y = lo[o4 * 4 + 1];
            v.z = lo[o4 * 4 + 2]; v.w = lo[o4 * 4 + 3];
            op[o4] = v;
        }
    }
}

// ---------------------------------------------------------------------------
// Pass A: coalesced split-K reduction -> compact bf16 sums.
__global__ __launch_bounds__(256) void reduce_k(const ushort* __restrict__ Gp,
        const ushort* __restrict__ PXp, ushort* __restrict__ Gsum,
        ushort* __restrict__ PXsum, int nzg, int nzp) {
    int idx = blockIdx.x * 256 + threadIdx.x;   // 81920 units of 8 elems
    if (idx < 73728) {
        size_t off = (size_t)idx * 8;
        float acc[8] = {0.f, 0.f, 0.f, 0.f, 0.f, 0.f, 0.f, 0.f};
        for (int zz = 0; zz < nzg; ++zz) {
            u16x8 v = *(const u16x8*)(Gp + (size_t)zz * 589824 + off);
#pragma unroll
            for (int u = 0; u < 8; ++u) acc[u] += b2f(v[u]);
        }
        u16x8 o;
#pragma unroll
        for (int u = 0; u < 8; ++u) o[u] = f2bf(acc[u]);
        *(u16x8*)(Gsum + off) = o;
    } else {
        size_t off = (size_t)(idx - 73728) * 8;
        float acc[8] = {0.f, 0.f, 0.f, 0.f, 0.f, 0.f, 0.f, 0.f};
        for (int zz = 0; zz < nzp; ++zz) {
            u16x8 v = *(const u16x8*)(PXp + (size_t)zz * 65536 + off);
#pragma unroll
            for (int u = 0; u < 8; ++u) acc[u] += b2f(v[u]);
        }
        u16x8 o;
#pragma unroll
        for (int u = 0; u < 8; ++u) o[u] = f2bf(acc[u]);
        *(u16x8*)(PXsum + off) = o;
    }
}

// ---------------------------------------------------------------------------
// Pass B: gather/mirror/swizzle of the L2-resident sums + zero next ssacc.
__global__ __launch_bounds__(256) void castgp_k(const ushort* __restrict__ Gsum,
        const ushort* __restrict__ PXsum, ushort* __restrict__ Gb,
        ushort* __restrict__ PtXTb, float* __restrict__ ssz) {
    if (blockIdx.x < 64) ssz[blockIdx.x * 256 + threadIdx.x] = 0.f;
    int idx = blockIdx.x * 256 + threadIdx.x;   // 278528 units
    if (idx < 262144) {
        int n = idx >> 8;
        int so = (idx & 255) * 4;
        int k0 = (so & ~63) | ((((so >> 3) & 7) ^ (n & 7)) << 3) | (so & 7);
        ushort po[4];
#pragma unroll
        for (int u = 0; u < 4; ++u) {
            int kk = k0 + u;
            int a = min(n, kk), b = max(n, kk);
            int tm = a >> 7, tn = b >> 7;
            int tlin = tm * 8 - ((tm * (tm - 1)) >> 1) + (tn - tm);
            size_t off = (size_t)tlin * 16384 + (size_t)(a & 127) * 128 + (b & 127);
            po[u] = (ushort)(Gsum[off] ^ 0x8000u);   // negate via sign bit
        }
        ushort4 o; o.x = po[0]; o.y = po[1]; o.z = po[2]; o.w = po[3];
        *(ushort4*)(Gb + (size_t)n * DIM + so) = o;
    } else {
        int vv = idx - 262144;                  // 16384 units
        int d = vv >> 4;
        int so = (vv & 15) * 4;
        int k0 = ((((so >> 3) & 7) ^ (d & 7)) << 3) | (so & 7);
        const ushort* src = PXsum + (size_t)d * OUTD + k0;
        ushort4 o; o.x = src[0]; o.y = src[1]; o.z = src[2]; o.w = src[3];
        *(ushort4*)(PtXTb + (size_t)d * OUTD + so) = o;
    }
}

// ---------------------------------------------------------------------------
// NT MFMA GEMM body (R5-proven).
template<int BM, int BN, int EPI, int TRI>
__device__ __forceinline__ void gemm_body(
        const ushort* __restrict__ A0, int lda0,
        const ushort* __restrict__ B0, int ldb0, int k0len,
        const ushort* __restrict__ A1, int lda1,
        const ushort* __restrict__ B1, int ldb1, int k1len,
        float* __restrict__ C, int ldc,
        const float* __restrict__ ssrd, float gamma,
        float* __restrict__ ssacc, int pstride, int nz,
        int bx, int by, int bz, ushort* ls) {
    constexpr int WTN = BN / 2;
    constexpr int NF = WTN / 16;
    constexpr int NAW = BM / 64;     // waves staging A
    constexpr int NBW = BN / 64;     // waves staging B
    ushort* lsA = ls;
    ushort* lsB = ls + BM * 64;
    int t = threadIdx.x;
    int wave = t >> 6, lane = t & 63;
    int rl = lane & 15, q = lane >> 4;
    int wm = wave & 1, wn = wave >> 1;
    int m0, n0, zidx, tlin = 0;
    if (TRI) {
        int bid = bx;
        int bxx, tm = 0;
        if (nz == 16) {                 // R7-proven mapping: grid 8*36*2
            int rest = bid >> 3;
            bxx = rest % 36;
            int zhi = rest / 36;
            zidx = (bid & 7) | (zhi << 3);
        } else {                        // fallback: grid 36*4
            zidx = bid & 3;
            bxx = bid >> 2;
        }
        tlin = bxx;
        while (bxx >= 8 - tm) { bxx -= 8 - tm; ++tm; }
        m0 = tm * 128; n0 = (tm + bxx) * 128;
    } else {
        m0 = bx * BM; n0 = by * BN; zidx = bz;
    }
    int lrow8 = lane >> 3, lgrp = lane & 7;
    bool isA = wave < NAW;
    bool active = wave < NAW + NBW;
    int wlocal = isA ? wave : wave - NAW;
    ushort* dstb = ls + (isA ? 0 : BM * 64) + wlocal * 4096;

    f32x4 acc[4][NF];
#pragma unroll
    for (int i = 0; i < 4; ++i)
#pragma unroll
        for (int j = 0; j < NF; ++j) acc[i][j] = f32x4{0.f, 0.f, 0.f, 0.f};
    float rvv[4][4];

    for (int seg = 0; seg < 2; ++seg) {
        int klen = seg ? k1len : k0len;
        if (klen > 0) {
            const ushort* OPA = seg ? A1 : A0;
            const ushort* OPB = seg ? B1 : B0;
            int ldaS = seg ? lda1 : lda0;
            int ldbS = seg ? ldb1 : ldb0;
            int kb = seg ? 0 : zidx * k0len;
            const ushort* srcb;
            size_t ldS;
            if (isA) {
                srcb = OPA + (size_t)(m0 + wlocal * 64 + lrow8) * ldaS + lgrp * 8;
                ldS = (size_t)ldaS;
            } else {
                srcb = OPB + (size_t)(n0 + wlocal * 64 + lrow8) * ldbS + lgrp * 8;
                ldS = (size_t)ldbS;
            }
            srcb += kb;
            for (int kt = 0; kt < klen; kt += 64) {
                if (active) {
#pragma unroll
                    for (int c = 0; c < 8; ++c)
                        __builtin_amdgcn_global_load_lds(AS1C(srcb + c * 8 * ldS),
                                                         AS3(dstb + c * 512), 16, 0, 0);
                    srcb += 64;
                }
                __syncthreads();
#pragma unroll
                for (int s = 0; s < 2; ++s) {
                    bf16x8 af[4], bfr[NF];
#pragma unroll
                    for (int i = 0; i < 4; ++i) {
                        int row = wm * 64 + i * 16 + rl;
                        int sg = ((s << 2) | q) ^ (row & 7);
                        af[i] = *(const bf16x8*)&lsA[row * 64 + sg * 8];
                    }
#pragma unroll
                    for (int j = 0; j < NF; ++j) {
                        int row = wn * WTN + j * 16 + rl;
                        int sg = ((s << 2) | q) ^ (row & 7);
                        bfr[j] = *(const bf16x8*)&lsB[row * 64 + sg * 8];
                    }
#pragma unroll
                    for (int i = 0; i < 4; ++i)
#pragma unroll
                        for (int j = 0; j < NF; ++j)
                            acc[i][j] = __builtin_amdgcn_mfma_f32_16x16x32_bf16(
                                af[i], bfr[j], acc[i][j], 0, 0, 0);
                }
                __syncthreads();
            }
        }
        if (EPI == 1 && seg == 0) {
#pragma unroll
            for (int i = 0; i < 4; ++i)
#pragma unroll
                for (int rg = 0; rg < 4; ++rg)
                    rvv[i][rg] = 1.0f / sqrtf(ssrd[m0 + wm * 64 + i * 16 + q * 4 + rg]);
#pragma unroll
            for (int i = 0; i < 4; ++i)
#pragma unroll
                for (int j = 0; j < NF; ++j)
#pragma unroll
                    for (int rg = 0; rg < 4; ++rg)
                        acc[i][j][rg] *= rvv[i][rg];
        }
    }

    if (EPI == 0) {
        ushort* Cb = (ushort*)C + (size_t)zidx * (size_t)pstride;
#pragma unroll
        for (int i = 0; i < 4; ++i)
#pragma unroll
            for (int j = 0; j < NF; ++j)
#pragma unroll
                for (int rg = 0; rg < 4; ++rg) {
                    float v = acc[i][j][rg];
                    float vp = __shfl_xor(v, 1);   // partner lane's (n^1) value
                    if ((rl & 1) == 0) {
                        int ml = wm * 64 + i * 16 + q * 4 + rg;
                        int nl = wn * WTN + j * 16 + rl;
                        size_t off;
                        if (TRI)
                            off = (size_t)tlin * (BM * BN) + (size_t)ml * BN + nl;
                        else
                            off = (size_t)(m0 + ml) * ldc + (n0 + nl);
                        unsigned pk = (unsigned)f2bf(v) | ((unsigned)f2bf(vp) << 16);
                        *(unsigned*)(Cb + off) = pk;
                    }
                }
    } else {
#pragma unroll
        for (int i = 0; i < 4; ++i)
#pragma unroll
            for (int rg = 0; rg < 4; ++rg) {
                int m = m0 + wm * 64 + i * 16 + q * 4 + rg;
                float ssl = 0.f;
#pragma unroll
                for (int j = 0; j < NF; ++j) {
                    int n = n0 + wn * WTN + j * 16 + rl;
                    int so = swz(n, m);
                    float base = b2f(A0[(size_t)m * lda0 + so]);
                    float vf = base * rvv[i][rg] + gamma * acc[i][j][rg];
                    ((ushort*)C)[(size_t)m * ldc + so] = f2bf(vf);
                    ssl += vf * vf;
                }
                ssl += __shfl_xor(ssl, 1);
                ssl += __shfl_xor(ssl, 2);
                ssl += __shfl_xor(ssl, 4);
                ssl += __shfl_xor(ssl, 8);
                if (rl == 0) atomicAdd(&ssacc[m], ssl);
            }
    }
}

template<int BM, int BN, int EPI, int TRI>
__global__ __launch_bounds__(256, 3) void gemm_nt_k(
        const ushort* __restrict__ A0, int lda0,
        const ushort* __restrict__ B0, int ldb0, int k0len,
        const ushort* __restrict__ A1, int lda1,
        const ushort* __restrict__ B1, int ldb1, int k1len,
        float* __restrict__ C, int ldc,
        const float* __restrict__ ssrd, float gamma,
        float* __restrict__ ssacc, int pstride, int nz) {
    __shared__ ushort ls[(BM + BN) * 64];
    gemm_body<BM, BN, EPI, TRI>(A0, lda0, B0, ldb0, k0len, A1, lda1, B1, ldb1,
        k1len, C, ldc, ssrd, gamma, ssacc, pstride, nz,
        blockIdx.x, blockIdx.y, blockIdx.z, ls);
}

// ---------------------------------------------------------------------------
// Fused G-gemm (blocks 0..575, TRI split-K 16) + PtX-gemm (576..831, split-K 32).
__global__ __launch_bounds__(256, 3) void gp_k(const ushort* __restrict__ XnT,
        const ushort* __restrict__ PTb, ushort* __restrict__ Gpart,
        ushort* __restrict__ PXpart) {
    __shared__ ushort ls[256 * 64];
    int bid = blockIdx.x;
    if (bid < 576) {
        gemm_body<128, 128, 0, 1>(XnT, N_ROWS, XnT, N_ROWS, 1024,
            nullptr, 0, nullptr, 0, 0,
            (float*)Gpart, 128, nullptr, 0.f, nullptr, 36 * 16384, 16,
            bid, 0, 0, ls);
    } else {
        int b2 = bid - 576;
        gemm_body<128, 64, 0, 0>(XnT, N_ROWS, PTb, N_ROWS, 512,
            nullptr, 0, nullptr, 0, 0,
            (float*)PXpart, OUTD, nullptr, 0.f, nullptr, DIM * OUTD, 0,
            b2 & 7, 0, b2 >> 3, ls);
    }
}

// ---------------------------------------------------------------------------
// R13 fixed 256^2 8-phase update gemm (rows half B of the A/B test).
// FIX 1: STG stages the swizzled master VERBATIM (src col grp*8) — the ds_read
// XOR ^(rl&7) then undoes it (R5-proven pairing). FIX 2: vmcnt(8) waits at
// p2/p6/p8 (drain distance 4-5 phases, steady in-flight 16 loads); last iter
// p6/p8 use vmcnt(0).
#define STG(OP, LD, ROW0, KCOL, DST, ISB, H) { \
    _Pragma("unroll") for (int l_ = 0; l_ < 2; ++l_) { \
        int flat_ = l_ * 512 + tid; \
        int grp_ = flat_ & 7, rih_ = flat_ >> 3; \
        int grow_ = (ISB) ? ((rih_ & 31) + (H) * 32 + (rih_ >> 5) * 64) \
                          : ((rih_ & 63) + (H) * 64 + (rih_ >> 6) * 128); \
        __builtin_amdgcn_global_load_lds( \
            AS1C((OP) + (size_t)((ROW0) + grow_) * (LD) + (KCOL) + (grp_ << 3)), \
            AS3((DST) + flat_ * 8), 16, 0, 0); } }

#define PHASE(BUF, MH, NH, STAGE_STMT, VM_STMT) { \
    const ushort* lA_ = ls + (BUF) * 32768 + (MH) * 8192; \
    const ushort* lB_ = ls + (BUF) * 32768 + 16384 + (NH) * 8192; \
    bf16x8 af_[4][2], bf_[2][2]; \
    _Pragma("unroll") for (int f_ = 0; f_ < 4; ++f_) \
        _Pragma("unroll") for (int ks_ = 0; ks_ < 2; ++ks_) \
            af_[f_][ks_] = *(const bf16x8*)&lA_[(wm2 * 64 + f_ * 16 + rl) * 64 \
                + (((ks_ << 2) | q) ^ (rl & 7)) * 8]; \
    _Pragma("unroll") for (int j_ = 0; j_ < 2; ++j_) \
        _Pragma("unroll") for (int ks_ = 0; ks_ < 2; ++ks_) \
            bf_[j_][ks_] = *(const bf16x8*)&lB_[(wn2 * 32 + j_ * 16 + rl) * 64 \
                + (((ks_ << 2) | q) ^ (rl & 7)) * 8]; \
    STAGE_STMT; \
    __builtin_amdgcn_s_barrier(); \
    asm volatile("s_waitcnt lgkmcnt(0)" ::: "memory"); \
    __builtin_amdgcn_sched_barrier(0); \
    __builtin_amdgcn_s_setprio(1); \
    _Pragma("unroll") for (int f_ = 0; f_ < 4; ++f_) \
        _Pragma("unroll") for (int j_ = 0; j_ < 2; ++j_) \
            _Pragma("unroll") for (int ks_ = 0; ks_ < 2; ++ks_) \
                acc[(MH) * 4 + f_][(NH) * 2 + j_] = \
                    __builtin_amdgcn_mfma_f32_16x16x32_bf16(af_[f_][ks_], \
                        bf_[j_][ks_], acc[(MH) * 4 + f_][(NH) * 2 + j_], 0, 0, 0); \
    __builtin_amdgcn_s_setprio(0); \
    VM_STMT; \
    __builtin_amdgcn_s_barrier(); }

__global__ __launch_bounds__(512, 1) void upd_k(
        const ushort* __restrict__ Xm, const ushort* __restrict__ Gb,
        const ushort* __restrict__ Pb, const ushort* __restrict__ PtXTb,
        ushort* __restrict__ Cm, const float* __restrict__ ssrd,
        float gamma, float* __restrict__ ssacc) {
    __shared__ ushort ls[65536];   // 128 KB: [buf][A|B][half][128][64]
    int tid = threadIdx.x;
    int wave = tid >> 6, lane = tid & 63;
    int rl = lane & 15, q = lane >> 4;
    int wm2 = wave >> 2, wn2 = wave & 3;   // 2M x 4N
    int m0 = blockIdx.x * 256, n0 = blockIdx.y * 256;

    f32x4 acc[8][4];
#pragma unroll
    for (int i = 0; i < 8; ++i)
#pragma unroll
        for (int j = 0; j < 4; ++j) acc[i][j] = f32x4{0.f, 0.f, 0.f, 0.f};

    // prologue: t0 full into buf0, t1 halves A0/B0 into buf1; drain once.
    STG(Xm, DIM, m0, 0,  ls,                 0, 0);   // b0.A.h0 <- t0
    STG(Gb, DIM, n0, 0,  ls + 16384,         1, 0);   // b0.B.h0 <- t0
    STG(Xm, DIM, m0, 0,  ls + 8192,          0, 1);   // b0.A.h1 <- t0
    STG(Gb, DIM, n0, 0,  ls + 24576,         1, 1);   // b0.B.h1 <- t0
    STG(Xm, DIM, m0, 64, ls + 32768,         0, 0);   // b1.A.h0 <- t1
    STG(Gb, DIM, n0, 64, ls + 49152,         1, 0);   // b1.B.h0 <- t1
    asm volatile("s_waitcnt vmcnt(0)" ::: "memory");
    __builtin_amdgcn_s_barrier();

    // main loop: 16 K-tiles (K=1024), 2 tiles/iter, 8 phases/iter.
    // p1,p2 stage t1 late halves (unconditional); p3-p6 stage t0+2; p7,p8
    // stage t1+2 early halves. vmcnt(8) at p2/p6/p8 (last iter: p6/p8 -> 0).
#pragma unroll 1
    for (int it = 0; it < 8; ++it) {
        int k1 = (2 * it + 1) * 64;
        int k2 = (2 * it + 2) * 64;
        int k3 = (2 * it + 3) * 64;
        bool pf = (it < 7);
        PHASE(0, 0, 0, STG(Xm, DIM, m0, k1, ls + 40960, 0, 1), );
        PHASE(0, 0, 1, STG(Gb, DIM, n0, k1, ls + 57344, 1, 1),
              asm volatile("s_waitcnt vmcnt(8)" ::: "memory"));
        PHASE(0, 1, 0, if (pf) STG(Xm, DIM, m0, k2, ls, 0, 0), );
        PHASE(0, 1, 1, if (pf) STG(Gb, DIM, n0, k2, ls + 16384, 1, 0), );
        PHASE(1, 0, 0, if (pf) STG(Xm, DIM, m0, k2, ls + 8192, 0, 1), );
        PHASE(1, 0, 1, if (pf) STG(Gb, DIM, n0, k2, ls + 24576, 1, 1),
              if (pf) { asm volatile("s_waitcnt vmcnt(8)" ::: "memory"); }
              else    { asm volatile("s_waitcnt vmcnt(0)" ::: "memory"); });
        PHASE(1, 1, 0, if (pf) STG(Xm, DIM, m0, k3, ls + 32768, 0, 0), );
        PHASE(1, 1, 1, if (pf) STG(Gb, DIM, n0, k3, ls + 49152, 1, 0),
              if (pf) { asm volatile("s_waitcnt vmcnt(8)" ::: "memory"); }
              else    { asm volatile("s_waitcnt vmcnt(0)" ::: "memory"); });
    }

    // seg1 staging (Pb/PtXTb, K=64) into buf0.
    STG(Pb,    OUTD, m0, 0, ls,         0, 0);
    STG(Pb,    OUTD, m0, 0, ls + 8192,  0, 1);
    STG(PtXTb, OUTD, n0, 0, ls + 16384, 1, 0);
    STG(PtXTb, OUTD, n0, 0, ls + 24576, 1, 1);

    // rvv scaling of seg0 accumulator (Xn@G needs rinv[m])
    float rvv[8][4];
#pragma unroll
    for (int i = 0; i < 8; ++i)
#pragma unroll
        for (int rg = 0; rg < 4; ++rg) {
            rvv[i][rg] = 1.0f / sqrtf(ssrd[m0 + wm2 * 128 + i * 16 + q * 4 + rg]);
#pragma unroll
            for (int j = 0; j < 4; ++j) acc[i][j][rg] *= rvv[i][rg];
        }
    __syncthreads();   // drains vmcnt(0) + barrier: seg1 tiles ready

    // seg1 compute: K=64 (all 4 quadrants), plain.
#pragma unroll
    for (int mh = 0; mh < 2; ++mh)
#pragma unroll
        for (int nh = 0; nh < 2; ++nh) {
            const ushort* lA_ = ls + mh * 8192;
            const ushort* lB_ = ls + 16384 + nh * 8192;
#pragma unroll
            for (int f = 0; f < 4; ++f)
#pragma unroll
                for (int j = 0; j < 2; ++j)
#pragma unroll
                    for (int ks = 0; ks < 2; ++ks) {
                        bf16x8 a8 = *(const bf16x8*)&lA_[(wm2 * 64 + f * 16 + rl) * 64
                            + (((ks << 2) | q) ^ (rl & 7)) * 8];
                        bf16x8 b8 = *(const bf16x8*)&lB_[(wn2 * 32 + j * 16 + rl) * 64
                            + (((ks << 2) | q) ^ (rl & 7)) * 8];
                        acc[mh * 4 + f][nh * 2 + j] =
                            __builtin_amdgcn_mfma_f32_16x16x32_bf16(a8, b8,
                                acc[mh * 4 + f][nh * 2 + j], 0, 0, 0);
                    }
        }

    // epilogue: vf = base*rinv + gamma*acc; write bf16 master + row ss atomics.
#pragma unroll
    for (int i = 0; i < 8; ++i)
#pragma unroll
        for (int rg = 0; rg < 4; ++rg) {
            int m = m0 + wm2 * 128 + i * 16 + q * 4 + rg;
            float ssl = 0.f;
#pragma unroll
            for (int j = 0; j < 4; ++j) {
                int n = n0 + wn2 * 64 + j * 16 + rl;
                int so = swz(n, m);
                float base = b2f(Xm[(size_t)m * DIM + so]);
                float vf = base * rvv[i][rg] + gamma * acc[i][j][rg];
                Cm[(size_t)m * DIM + so] = f2bf(vf);
                ssl += vf * vf;
            }
            ssl += __shfl_xor(ssl, 1);
            ssl += __shfl_xor(ssl, 2);
            ssl += __shfl_xor(ssl, 4);
            ssl += __shfl_xor(ssl, 8);
            if (rl == 0) atomicAdd(&ssacc[m], ssl);
        }
}

// ---------------------------------------------------------------------------
extern "C" void kernel_launch(void* const* d_in, const int* in_sizes, int n_in,
                              void* d_out, int out_size, void* d_ws, size_t ws_size,
                              hipStream_t stream) {
    const float* X = (const float*)d_in[0];
    const float* W1 = (const float*)d_in[1];
    const float* b1 = (const float*)d_in[2];
    const float* W2 = (const float*)d_in[3];
    const float* b2 = (const float*)d_in[4];
    float* out = (float*)d_out;
    char* ws = (char*)d_ws;

    constexpr size_t O_BufA    = 0;                                     // 33,554,432
    constexpr size_t O_BufB    = O_BufA + (size_t)N_ROWS * DIM * 2;     // 33,554,432
    constexpr size_t O_Pb      = O_BufB + (size_t)N_ROWS * DIM * 2;     //  2,097,152
    constexpr size_t O_PTb     = O_Pb + (size_t)N_ROWS * OUTD * 2;      //  2,097,152
    constexpr size_t O_Gb      = O_PTb + (size_t)OUTD * N_ROWS * 2;     //  2,097,152
    constexpr size_t O_PtXTb   = O_Gb + (size_t)DIM * DIM * 2;          //    131,072
    constexpr size_t O_ssB     = O_PtXTb + (size_t)DIM * OUTD * 2;      //     65,536
    constexpr size_t O_W1T     = O_ssB + (size_t)N_ROWS * 4;            //     32,768
    constexpr size_t O_ssA     = O_W1T + (size_t)HID * DIM * 2;         //     65,536
    constexpr size_t O_scratch = O_ssA + (size_t)N_ROWS * 4;            // = 73,695,232
    constexpr size_t WS_BIG = O_scratch + (size_t)16 * 589824 * 2;

    ushort* bufA  = (ushort*)(ws + O_BufA);
    ushort* bufB  = (ushort*)(ws + O_BufB);
    ushort* Pb    = (ushort*)(ws + O_Pb);
    ushort* PTb   = (ushort*)(ws + O_PTb);
    ushort* Gb    = (ushort*)(ws + O_Gb);
    ushort* PtXTb = (ushort*)(ws + O_PtXTb);
    float*  ssB   = (float*)(ws + O_ssB);
    ushort* W1T   = (ushort*)(ws + O_W1T);
    float*  ssA   = (float*)(ws + O_ssA);
    float*  z     = (float*)(ws + O_scratch);
    ushort* Gpart = (ushort*)(ws + O_scratch);
    ushort* PXpart = (ushort*)d_out;
    ushort* Gsum  = PTb;                       // PTb region reuse (dead)
    ushort* PXsum = PTb + 589824;
    (void)in_sizes; (void)n_in; (void)out_size;

    const bool big = ws_size >= WS_BIG;
    const int nzg = big ? 16 : 4;
    const int nzp = big ? 32 : 8;

    prep_w1t_k<<<64, 256, 0, stream>>>(W1, W1T);
    tobf16_k<<<N_ROWS, 256, 0, stream>>>(X, bufA, ssA);

    ushort* xm  = bufA;
    ushort* alt = bufB;
    float* ssCur = ssA;
    float* ssNxt = ssB;

    for (int it = 0; it < DEPTH; ++it) {
        if (big) {
            txz_k<<<4096 + 256, 256, 0, stream>>>(xm, ssCur, alt, W1T, b1, z);
        } else {
            transpose_k<<<dim3(N_ROWS / 64, DIM / 64), 256, 0, stream>>>(xm, ssCur, alt);
            zgemm_k<<<N_ROWS / 64, 256, 0, stream>>>(xm, W1T, b1, z, ssCur);
        }
        head_k<<<N_ROWS / 256, 256, 0, stream>>>(z, W2, b2, Pb, PTb, nullptr, 1);
        if (big) {
            gp_k<<<576 + 256, 256, 0, stream>>>(alt, PTb, Gpart, PXpart);
        } else {
            gemm_nt_k<128, 128, 0, 1><<<dim3(36 * 4, 1, 1), 256, 0, stream>>>(
                alt, N_ROWS, alt, N_ROWS, 4096,
                nullptr, 0, nullptr, 0, 0,
                (float*)Gpart, 128, nullptr, 0.f, nullptr, 36 * 16384, 4);
            gemm_nt_k<128, 64, 0, 0><<<dim3(8, 1, 8), 256, 0, stream>>>(
                alt, N_ROWS, PTb, N_ROWS, 2048,
                nullptr, 0, nullptr, 0, 0,
                (float*)PXpart, OUTD, nullptr, 0.f, nullptr, DIM * OUTD, 0);
        }
        reduce_k<<<320, 256, 0, stream>>>(Gpart, PXpart, Gsum, PXsum, nzg, nzp);
        castgp_k<<<1088, 256, 0, stream>>>(Gsum, PXsum, Gb, PtXTb, ssNxt);
        // ---- A/B: update gemm split by m-rows ----
        // half A (rows 0..8191): proven 2-barrier EPI1
        gemm_nt_k<128, 128, 1, 0><<<dim3(64, DIM / 128, 1), 256, 0, stream>>>(
            xm, DIM, Gb, DIM, 1024,
            Pb, OUTD, PtXTb, OUTD, OUTD,
            (float*)alt, DIM, ssCur, GAMMA, ssNxt, 0, 0);
        // half B (rows 8192..16383): fixed 8-phase upd_k (offset ptrs, 8192%8==0)
        upd_k<<<dim3(32, DIM / 256, 1), 512, 0, stream>>>(
            xm + (size_t)8192 * DIM, Gb, Pb + (size_t)8192 * OUTD, PtXTb,
            alt + (size_t)8192 * DIM, ssCur + 8192, GAMMA, ssNxt + 8192);
        ushort* tmp = xm; xm = alt; alt = tmp;
        float* ts2 = ssCur; ssCur = ssNxt; ssNxt = ts2;
    }

    zgemm_k<<<N_ROWS / 64, 256, 0, stream>>>(xm, W1T, b1, z, nullptr);
    head_k<<<N_ROWS / 256, 256, 0, stream>>>(z, W2, b2, Pb, PTb, out, 0);
}

// Round 7
// 1088.021 us; speedup vs baseline: 1.0554x; 1.0554x over previous
//
#include <hip/hip_runtime.h>

// CKAFormer R14 (from R13; R13 A/B post-mortem: 8-phase upd_k did HALF the
// rows in 59.7us = the time 2-barrier EPI1 takes for ALL rows — ~2x slower
// per row even after the swizzle+vmcnt fixes. Cause: 128KB LDS -> 1 block/CU,
// 128-block grid -> half the CUs idle (Occ 9.3%), and the heavy epilogue
// isn't helped by the schedule. VERDICT: 8-phase abandoned for this op; the
// 2-barrier 128^2 structure at ~3 blocks/CU is the right regime.
// R14 = exact R11 revert (proven 908.7us) + ONE surgical EPI1 change:
// - EPI1 epilogue base (Xm[m][swz(n,m)], was 64 scattered global ushort
//   loads/thread) is CAPTURED FROM LDS during the K-loop: epilogue n-columns
//   are a subset of the K-range (both DIM), so when kt == n0+wn*WTN (wave-
//   uniform, always hit in seg0) the staged A-tile IS the base block. 64 bf16
//   packed into 32 u32 VGPRs (static indexing). Saves ~13MB scattered fetch
//   + tail latency per dispatch. VGPR 60->~95 < lb(256,3) cap 170. EPI0
//   instantiations unaffected (capture is EPI==1-only, DCE'd).

#define N_ROWS 16384
#define DIM 1024
#define HID 16
#define OUTD 64
#define DEPTH 6
#define GAMMA 1e-4f

typedef short bf16x8 __attribute__((ext_vector_type(8)));
typedef unsigned short u16x8 __attribute__((ext_vector_type(8)));
typedef float f32x4 __attribute__((ext_vector_type(4)));

#define AS1C(p) ((const __attribute__((address_space(1))) void*)(p))
#define AS3(p)  ((__attribute__((address_space(3))) void*)(p))

__device__ __forceinline__ unsigned short f2bf(float f) {
    unsigned u = __builtin_bit_cast(unsigned, f);
    u += 0x7fffu + ((u >> 16) & 1u);   // round-to-nearest-even
    return (unsigned short)(u >> 16);
}
__device__ __forceinline__ float b2f(ushort u) {
    unsigned x = ((unsigned)u) << 16;
    return __builtin_bit_cast(float, x);
}
// stored offset of logical element n within a swizzled row keyed by (row&7)
__device__ __forceinline__ int swz(int n, int row) {
    return (n & ~63) | ((((n >> 3) & 7) ^ (row & 7)) << 3) | (n & 7);
}

// ---------------------------------------------------------------------------
// Once per launch: master Xm = bf16(X) swizzled rows + ssout[row] = ||X[row]||^2.
__global__ __launch_bounds__(256) void tobf16_k(const float* __restrict__ X,
        ushort* __restrict__ Xm, float* __restrict__ ssout) {
    int row = blockIdx.x, t = threadIdx.x;
    float4 v = ((const float4*)(X + (size_t)row * DIM))[t];
    ushort4 o4;
    o4.x = f2bf(v.x); o4.y = f2bf(v.y); o4.z = f2bf(v.z); o4.w = f2bf(v.w);
    *(ushort4*)(Xm + (size_t)row * DIM + swz(t * 4, row)) = o4;
    float ss = v.x * v.x + v.y * v.y + v.z * v.z + v.w * v.w;
    for (int o = 32; o > 0; o >>= 1) ss += __shfl_down(ss, o);
    __shared__ float wsum[4];
    if ((t & 63) == 0) wsum[t >> 6] = ss;
    __syncthreads();
    if (t == 0) ssout[row] = wsum[0] + wsum[1] + wsum[2] + wsum[3];
}

// ---------------------------------------------------------------------------
// XnT[d][k] = bf16(Xm[k][d] / ||X[k]||), swizzled by d. LDS 64x65 f32 tile.
__device__ __forceinline__ void transpose_body(const ushort* __restrict__ Xm,
        const float* __restrict__ ss, ushort* __restrict__ XnT,
        int bx, int by, float* ts, float* riS) {
    int r0 = bx * 64;   // source row (k) tile
    int c0 = by * 64;   // source col (d) tile
    int t = threadIdx.x;
    if (t < 64) riS[t] = 1.0f / sqrtf(ss[r0 + t]);
    __syncthreads();
#pragma unroll
    for (int i = 0; i < 2; ++i) {
        int idx = i * 256 + t;
        int r = idx >> 3, lg = idx & 7;
        int rr = r0 + r;
        const ushort* p = Xm + (size_t)rr * DIM + c0 + ((lg ^ (rr & 7)) << 3);
        u16x8 a = *(const u16x8*)p;
        float s = riS[r];
        float* d = &ts[r * 65 + lg * 8];
#pragma unroll
        for (int u = 0; u < 8; ++u) d[u] = b2f(a[u]) * s;
    }
    __syncthreads();
#pragma unroll
    for (int i = 0; i < 2; ++i) {
        int g = i * 256 + t;
        int c = g >> 3;
        int rg = g & 7;
        u16x8 pk;
#pragma unroll
        for (int u = 0; u < 8; ++u) pk[u] = f2bf(ts[(rg * 8 + u) * 65 + c]);
        *(u16x8*)(XnT + (size_t)(c0 + c) * N_ROWS + r0 + ((rg ^ (c & 7)) << 3)) = pk;
    }
}

// ---------------------------------------------------------------------------
// z[m][h] = (Xm[m]·W1[:,h]) / ||X[m]|| + b1[h]   (ss=nullptr -> no scale; final).
__device__ __forceinline__ void zgemm_body(const ushort* __restrict__ Xm,
        const ushort* __restrict__ W1T, const float* __restrict__ b1,
        float* __restrict__ z, const float* __restrict__ ss, int bidx) {
    int t = threadIdx.x;
    int wave = t >> 6, lane = t & 63;
    int rl = lane & 15, q = lane >> 4;
    int rowbase = bidx * 64 + wave * 16;
    int m = rowbase + rl;
    int msw = m & 7;
    const ushort* arow = Xm + (size_t)m * DIM;
    const ushort* brow = W1T + (size_t)rl * DIM + q * 8;
    f32x4 acc = {0.f, 0.f, 0.f, 0.f};
#pragma unroll 8
    for (int kt = 0; kt < DIM; kt += 32) {
        int gl = ((kt >> 3) & 7) | q;
        int off = (kt & ~63) + ((gl ^ msw) << 3);
        bf16x8 a = *(const bf16x8*)(arow + off);
        bf16x8 b = *(const bf16x8*)(brow + kt);
        acc = __builtin_amdgcn_mfma_f32_16x16x32_bf16(a, b, acc, 0, 0, 0);
    }
#pragma unroll
    for (int rg = 0; rg < 4; ++rg) {
        int mm = rowbase + q * 4 + rg;
        float s = ss ? 1.0f / sqrtf(ss[mm]) : 1.0f;
        z[(size_t)mm * HID + rl] = acc[rg] * s + b1[rl];
    }
}

// ---------------------------------------------------------------------------
// Fused transpose (blocks 0..4095) + zgemm (blocks 4096..4351).
__global__ __launch_bounds__(256) void txz_k(const ushort* __restrict__ Xm,
        const float* __restrict__ ss, ushort* __restrict__ XnT,
        const ushort* __restrict__ W1T, const float* __restrict__ b1,
        float* __restrict__ z) {
    __shared__ float ts[64 * 65];
    __shared__ float riS[64];
    int bid = blockIdx.x;
    if (bid < 4096) transpose_body(Xm, ss, XnT, bid & 255, bid >> 8, ts, riS);
    else            zgemm_body(Xm, W1T, b1, z, ss, bid - 4096);
}

// standalone wrappers (small path / final)
__global__ __launch_bounds__(256) void transpose_k(const ushort* __restrict__ Xm,
        const float* __restrict__ ss, ushort* __restrict__ XnT) {
    __shared__ float ts[64 * 65];
    __shared__ float riS[64];
    transpose_body(Xm, ss, XnT, blockIdx.x, blockIdx.y, ts, riS);
}
__global__ __launch_bounds__(256) void zgemm_k(const ushort* __restrict__ Xm,
        const ushort* __restrict__ W1T, const float* __restrict__ b1,
        float* __restrict__ z, const float* __restrict__ ss) {
    zgemm_body(Xm, W1T, b1, z, ss, blockIdx.x);
}

// ---------------------------------------------------------------------------
__global__ __launch_bounds__(256) void prep_w1t_k(const float* __restrict__ W1,
        ushort* __restrict__ W1T) {
    int idx = blockIdx.x * 256 + threadIdx.x;   // 16384
    int h = idx >> 10, j = idx & 1023;
    W1T[idx] = f2bf(W1[j * HID + h]);
}

// ---------------------------------------------------------------------------
// Per row: h = relu(z); logits = h@W2 + b2; softmax -> Pb (swizzled by m&7)
// + PTb (rows o, swizzled by o&7), or (do_softmax=0) logits f32 to out.
__global__ __launch_bounds__(256) void head_k(const float* __restrict__ z,
        const float* __restrict__ W2, const float* __restrict__ b2,
        ushort* __restrict__ Pb, ushort* __restrict__ PTb,
        float* __restrict__ out, int do_softmax) {
    __shared__ float w2s[HID * OUTD];
    __shared__ float b2s[OUTD];
    int t = threadIdx.x;
    ((float4*)w2s)[t] = ((const float4*)W2)[t];
    if (t < OUTD) b2s[t] = b2[t];
    __syncthreads();
    int m = blockIdx.x * 256 + t;
    float h[HID];
    const float4* zp = (const float4*)(z + (size_t)m * HID);
#pragma unroll
    for (int i = 0; i < 4; ++i) {
        float4 v = zp[i];
        h[i * 4 + 0] = fmaxf(v.x, 0.f); h[i * 4 + 1] = fmaxf(v.y, 0.f);
        h[i * 4 + 2] = fmaxf(v.z, 0.f); h[i * 4 + 3] = fmaxf(v.w, 0.f);
    }
    float lo[OUTD];
#pragma unroll
    for (int o = 0; o < OUTD; ++o) lo[o] = b2s[o];
    for (int i = 0; i < HID; ++i) {
        float hv = h[i];
#pragma unroll
        for (int o = 0; o < OUTD; ++o) lo[o] += hv * w2s[i * OUTD + o];
    }
    if (do_softmax) {
        float mx = lo[0];
#pragma unroll
        for (int o = 1; o < OUTD; ++o) mx = fmaxf(mx, lo[o]);
        float sm = 0.f;
#pragma unroll
        for (int o = 0; o < OUTD; ++o) { float e = __expf(lo[o] - mx); lo[o] = e; sm += e; }
        float inv = 1.0f / sm;
#pragma unroll
        for (int o8 = 0; o8 < 8; ++o8) {
            u16x8 pk;
#pragma unroll
            for (int u = 0; u < 8; ++u) pk[u] = f2bf(lo[o8 * 8 + u] * inv);
            ((u16x8*)(Pb + (size_t)m * OUTD))[o8 ^ (m & 7)] = pk;
        }
#pragma unroll
        for (int o = 0; o < OUTD; ++o)
            PTb[(size_t)o * N_ROWS + swz(m, o)] = f2bf(lo[o] * inv);
    } else {
        float4* op = (float4*)(out + (size_t)m * OUTD);
#pragma unroll
        for (int o4 = 0; o4 < 16; ++o4) {
            float4 v; v.x = lo[o4 * 4 + 0]; v.y = lo[o4 * 4 + 1];
            v.z = lo[o4 * 4 + 2]; v.w = lo[o4 * 4 + 3];
            op[o4] = v;
        }
    }
}

// ---------------------------------------------------------------------------
// Pass A: coalesced split-K reduction -> compact bf16 sums.
__global__ __launch_bounds__(256) void reduce_k(const ushort* __restrict__ Gp,
        const ushort* __restrict__ PXp, ushort* __restrict__ Gsum,
        ushort* __restrict__ PXsum, int nzg, int nzp) {
    int idx = blockIdx.x * 256 + threadIdx.x;   // 81920 units of 8 elems
    if (idx < 73728) {
        size_t off = (size_t)idx * 8;
        float acc[8] = {0.f, 0.f, 0.f, 0.f, 0.f, 0.f, 0.f, 0.f};
        for (int zz = 0; zz < nzg; ++zz) {
            u16x8 v = *(const u16x8*)(Gp + (size_t)zz * 589824 + off);
#pragma unroll
            for (int u = 0; u < 8; ++u) acc[u] += b2f(v[u]);
        }
        u16x8 o;
#pragma unroll
        for (int u = 0; u < 8; ++u) o[u] = f2bf(acc[u]);
        *(u16x8*)(Gsum + off) = o;
    } else {
        size_t off = (size_t)(idx - 73728) * 8;
        float acc[8] = {0.f, 0.f, 0.f, 0.f, 0.f, 0.f, 0.f, 0.f};
        for (int zz = 0; zz < nzp; ++zz) {
            u16x8 v = *(const u16x8*)(PXp + (size_t)zz * 65536 + off);
#pragma unroll
            for (int u = 0; u < 8; ++u) acc[u] += b2f(v[u]);
        }
        u16x8 o;
#pragma unroll
        for (int u = 0; u < 8; ++u) o[u] = f2bf(acc[u]);
        *(u16x8*)(PXsum + off) = o;
    }
}

// ---------------------------------------------------------------------------
// Pass B: gather/mirror/swizzle of the L2-resident sums + zero next ssacc.
__global__ __launch_bounds__(256) void castgp_k(const ushort* __restrict__ Gsum,
        const ushort* __restrict__ PXsum, ushort* __restrict__ Gb,
        ushort* __restrict__ PtXTb, float* __restrict__ ssz) {
    if (blockIdx.x < 64) ssz[blockIdx.x * 256 + threadIdx.x] = 0.f;
    int idx = blockIdx.x * 256 + threadIdx.x;   // 278528 units
    if (idx < 262144) {
        int n = idx >> 8;
        int so = (idx & 255) * 4;
        int k0 = (so & ~63) | ((((so >> 3) & 7) ^ (n & 7)) << 3) | (so & 7);
        ushort po[4];
#pragma unroll
        for (int u = 0; u < 4; ++u) {
            int kk = k0 + u;
            int a = min(n, kk), b = max(n, kk);
            int tm = a >> 7, tn = b >> 7;
            int tlin = tm * 8 - ((tm * (tm - 1)) >> 1) + (tn - tm);
            size_t off = (size_t)tlin * 16384 + (size_t)(a & 127) * 128 + (b & 127);
            po[u] = (ushort)(Gsum[off] ^ 0x8000u);   // negate via sign bit
        }
        ushort4 o; o.x = po[0]; o.y = po[1]; o.z = po[2]; o.w = po[3];
        *(ushort4*)(Gb + (size_t)n * DIM + so) = o;
    } else {
        int vv = idx - 262144;                  // 16384 units
        int d = vv >> 4;
        int so = (vv & 15) * 4;
        int k0 = ((((so >> 3) & 7) ^ (d & 7)) << 3) | (so & 7);
        const ushort* src = PXsum + (size_t)d * OUTD + k0;
        ushort4 o; o.x = src[0]; o.y = src[1]; o.z = src[2]; o.w = src[3];
        *(ushort4*)(PtXTb + (size_t)d * OUTD + so) = o;
    }
}

// ---------------------------------------------------------------------------
// NT MFMA GEMM body (R5-proven). R14: EPI1 captures the epilogue base from
// LDS at the K-tile kt == n0 + wn*WTN (wave-uniform; the staged A-tile holds
// exactly the stored columns [kt, kt+64) verbatim, and swz(n,m) for this
// wave's epilogue n-range lies in that window).
template<int BM, int BN, int EPI, int TRI>
__device__ __forceinline__ void gemm_body(
        const ushort* __restrict__ A0, int lda0,
        const ushort* __restrict__ B0, int ldb0, int k0len,
        const ushort* __restrict__ A1, int lda1,
        const ushort* __restrict__ B1, int ldb1, int k1len,
        float* __restrict__ C, int ldc,
        const float* __restrict__ ssrd, float gamma,
        float* __restrict__ ssacc, int pstride, int nz,
        int bx, int by, int bz, ushort* ls) {
    constexpr int WTN = BN / 2;
    constexpr int NF = WTN / 16;
    constexpr int NAW = BM / 64;     // waves staging A
    constexpr int NBW = BN / 64;     // waves staging B
    ushort* lsA = ls;
    ushort* lsB = ls + BM * 64;
    int t = threadIdx.x;
    int wave = t >> 6, lane = t & 63;
    int rl = lane & 15, q = lane >> 4;
    int wm = wave & 1, wn = wave >> 1;
    int m0, n0, zidx, tlin = 0;
    if (TRI) {
        int bid = bx;
        int bxx, tm = 0;
        if (nz == 16) {                 // R7-proven mapping: grid 8*36*2
            int rest = bid >> 3;
            bxx = rest % 36;
            int zhi = rest / 36;
            zidx = (bid & 7) | (zhi << 3);
        } else {                        // fallback: grid 36*4
            zidx = bid & 3;
            bxx = bid >> 2;
        }
        tlin = bxx;
        while (bxx >= 8 - tm) { bxx -= 8 - tm; ++tm; }
        m0 = tm * 128; n0 = (tm + bxx) * 128;
    } else {
        m0 = bx * BM; n0 = by * BN; zidx = bz;
    }
    int lrow8 = lane >> 3, lgrp = lane & 7;
    bool isA = wave < NAW;
    bool active = wave < NAW + NBW;
    int wlocal = isA ? wave : wave - NAW;
    ushort* dstb = ls + (isA ? 0 : BM * 64) + wlocal * 4096;

    f32x4 acc[4][NF];
#pragma unroll
    for (int i = 0; i < 4; ++i)
#pragma unroll
        for (int j = 0; j < NF; ++j) acc[i][j] = f32x4{0.f, 0.f, 0.f, 0.f};
    float rvv[4][4];
    // EPI1 epilogue base, captured from LDS (bf16 pairs packed in u32).
    unsigned basep[4][4][(NF / 2) > 0 ? (NF / 2) : 1];

    for (int seg = 0; seg < 2; ++seg) {
        int klen = seg ? k1len : k0len;
        if (klen > 0) {
            const ushort* OPA = seg ? A1 : A0;
            const ushort* OPB = seg ? B1 : B0;
            int ldaS = seg ? lda1 : lda0;
            int ldbS = seg ? ldb1 : ldb0;
            int kb = seg ? 0 : zidx * k0len;
            const ushort* srcb;
            size_t ldS;
            if (isA) {
                srcb = OPA + (size_t)(m0 + wlocal * 64 + lrow8) * ldaS + lgrp * 8;
                ldS = (size_t)ldaS;
            } else {
                srcb = OPB + (size_t)(n0 + wlocal * 64 + lrow8) * ldbS + lgrp * 8;
                ldS = (size_t)ldbS;
            }
            srcb += kb;
            for (int kt = 0; kt < klen; kt += 64) {
                if (active) {
#pragma unroll
                    for (int c = 0; c < 8; ++c)
                        __builtin_amdgcn_global_load_lds(AS1C(srcb + c * 8 * ldS),
                                                         AS3(dstb + c * 512), 16, 0, 0);
                    srcb += 64;
                }
                __syncthreads();
#pragma unroll
                for (int s = 0; s < 2; ++s) {
                    bf16x8 af[4], bfr[NF];
#pragma unroll
                    for (int i = 0; i < 4; ++i) {
                        int row = wm * 64 + i * 16 + rl;
                        int sg = ((s << 2) | q) ^ (row & 7);
                        af[i] = *(const bf16x8*)&lsA[row * 64 + sg * 8];
                    }
#pragma unroll
                    for (int j = 0; j < NF; ++j) {
                        int row = wn * WTN + j * 16 + rl;
                        int sg = ((s << 2) | q) ^ (row & 7);
                        bfr[j] = *(const bf16x8*)&lsB[row * 64 + sg * 8];
                    }
#pragma unroll
                    for (int i = 0; i < 4; ++i)
#pragma unroll
                        for (int j = 0; j < NF; ++j)
                            acc[i][j] = __builtin_amdgcn_mfma_f32_16x16x32_bf16(
                                af[i], bfr[j], acc[i][j], 0, 0, 0);
                }
                if (EPI == 1 && seg == 0 && kt == n0 + wn * WTN) {
                    // capture epilogue base: lsA[lrow*64 + c] = A0[(m0+lrow)*lda + kt + c]
#pragma unroll
                    for (int i2 = 0; i2 < 4; ++i2)
#pragma unroll
                        for (int rg2 = 0; rg2 < 4; ++rg2) {
                            int lrow = wm * 64 + i2 * 16 + q * 4 + rg2;
                            int mg = m0 + lrow;
#pragma unroll
                            for (int jp = 0; jp < NF / 2; ++jp) {
                                int na = n0 + wn * WTN + (2 * jp) * 16 + rl;
                                int nb = na + 16;
                                unsigned lo = lsA[lrow * 64 + (swz(na, mg) & 63)];
                                unsigned hi = lsA[lrow * 64 + (swz(nb, mg) & 63)];
                                basep[i2][rg2][jp] = lo | (hi << 16);
                            }
                        }
                }
                __syncthreads();
            }
        }
        if (EPI == 1 && seg == 0) {
#pragma unroll
            for (int i = 0; i < 4; ++i)
#pragma unroll
                for (int rg = 0; rg < 4; ++rg)
                    rvv[i][rg] = 1.0f / sqrtf(ssrd[m0 + wm * 64 + i * 16 + q * 4 + rg]);
#pragma unroll
            for (int i = 0; i < 4; ++i)
#pragma unroll
                for (int j = 0; j < NF; ++j)
#pragma unroll
                    for (int rg = 0; rg < 4; ++rg)
                        acc[i][j][rg] *= rvv[i][rg];
        }
    }

    if (EPI == 0) {
        ushort* Cb = (ushort*)C + (size_t)zidx * (size_t)pstride;
#pragma unroll
        for (int i = 0; i < 4; ++i)
#pragma unroll
            for (int j = 0; j < NF; ++j)
#pragma unroll
                for (int rg = 0; rg < 4; ++rg) {
                    float v = acc[i][j][rg];
                    float vp = __shfl_xor(v, 1);   // partner lane's (n^1) value
                    if ((rl & 1) == 0) {
                        int ml = wm * 64 + i * 16 + q * 4 + rg;
                        int nl = wn * WTN + j * 16 + rl;
                        size_t off;
                        if (TRI)
                            off = (size_t)tlin * (BM * BN) + (size_t)ml * BN + nl;
                        else
                            off = (size_t)(m0 + ml) * ldc + (n0 + nl);
                        unsigned pk = (unsigned)f2bf(v) | ((unsigned)f2bf(vp) << 16);
                        *(unsigned*)(Cb + off) = pk;
                    }
                }
    } else {
#pragma unroll
        for (int i = 0; i < 4; ++i)
#pragma unroll
            for (int rg = 0; rg < 4; ++rg) {
                int m = m0 + wm * 64 + i * 16 + q * 4 + rg;
                float ssl = 0.f;
#pragma unroll
                for (int j = 0; j < NF; ++j) {
                    int n = n0 + wn * WTN + j * 16 + rl;
                    int so = swz(n, m);
                    ushort bu = (ushort)((basep[i][rg][j >> 1] >> ((j & 1) * 16)) & 0xffffu);
                    float vf = b2f(bu) * rvv[i][rg] + gamma * acc[i][j][rg];
                    ((ushort*)C)[(size_t)m * ldc + so] = f2bf(vf);
                    ssl += vf * vf;
                }
                ssl += __shfl_xor(ssl, 1);
                ssl += __shfl_xor(ssl, 2);
                ssl += __shfl_xor(ssl, 4);
                ssl += __shfl_xor(ssl, 8);
                if (rl == 0) atomicAdd(&ssacc[m], ssl);
            }
    }
}

template<int BM, int BN, int EPI, int TRI>
__global__ __launch_bounds__(256, 3) void gemm_nt_k(
        const ushort* __restrict__ A0, int lda0,
        const ushort* __restrict__ B0, int ldb0, int k0len,
        const ushort* __restrict__ A1, int lda1,
        const ushort* __restrict__ B1, int ldb1, int k1len,
        float* __restrict__ C, int ldc,
        const float* __restrict__ ssrd, float gamma,
        float* __restrict__ ssacc, int pstride, int nz) {
    __shared__ ushort ls[(BM + BN) * 64];
    gemm_body<BM, BN, EPI, TRI>(A0, lda0, B0, ldb0, k0len, A1, lda1, B1, ldb1,
        k1len, C, ldc, ssrd, gamma, ssacc, pstride, nz,
        blockIdx.x, blockIdx.y, blockIdx.z, ls);
}

// ---------------------------------------------------------------------------
// Fused G-gemm (blocks 0..575, TRI split-K 16) + PtX-gemm (576..831, split-K 32).
__global__ __launch_bounds__(256, 3) void gp_k(const ushort* __restrict__ XnT,
        const ushort* __restrict__ PTb, ushort* __restrict__ Gpart,
        ushort* __restrict__ PXpart) {
    __shared__ ushort ls[256 * 64];
    int bid = blockIdx.x;
    if (bid < 576) {
        gemm_body<128, 128, 0, 1>(XnT, N_ROWS, XnT, N_ROWS, 1024,
            nullptr, 0, nullptr, 0, 0,
            (float*)Gpart, 128, nullptr, 0.f, nullptr, 36 * 16384, 16,
            bid, 0, 0, ls);
    } else {
        int b2 = bid - 576;
        gemm_body<128, 64, 0, 0>(XnT, N_ROWS, PTb, N_ROWS, 512,
            nullptr, 0, nullptr, 0, 0,
            (float*)PXpart, OUTD, nullptr, 0.f, nullptr, DIM * OUTD, 0,
            b2 & 7, 0, b2 >> 3, ls);
    }
}

// ---------------------------------------------------------------------------
extern "C" void kernel_launch(void* const* d_in, const int* in_sizes, int n_in,
                              void* d_out, int out_size, void* d_ws, size_t ws_size,
                              hipStream_t stream) {
    const float* X = (const float*)d_in[0];
    const float* W1 = (const float*)d_in[1];
    const float* b1 = (const float*)d_in[2];
    const float* W2 = (const float*)d_in[3];
    const float* b2 = (const float*)d_in[4];
    float* out = (float*)d_out;
    char* ws = (char*)d_ws;

    constexpr size_t O_BufA    = 0;                                     // 33,554,432
    constexpr size_t O_BufB    = O_BufA + (size_t)N_ROWS * DIM * 2;     // 33,554,432
    constexpr size_t O_Pb      = O_BufB + (size_t)N_ROWS * DIM * 2;     //  2,097,152
    constexpr size_t O_PTb     = O_Pb + (size_t)N_ROWS * OUTD * 2;      //  2,097,152
    constexpr size_t O_Gb      = O_PTb + (size_t)OUTD * N_ROWS * 2;     //  2,097,152
    constexpr size_t O_PtXTb   = O_Gb + (size_t)DIM * DIM * 2;          //    131,072
    constexpr size_t O_ssB     = O_PtXTb + (size_t)DIM * OUTD * 2;      //     65,536
    constexpr size_t O_W1T     = O_ssB + (size_t)N_ROWS * 4;            //     32,768
    constexpr size_t O_ssA     = O_W1T + (size_t)HID * DIM * 2;         //     65,536
    constexpr size_t O_scratch = O_ssA + (size_t)N_ROWS * 4;            // = 73,695,232
    constexpr size_t WS_BIG = O_scratch + (size_t)16 * 589824 * 2;

    ushort* bufA  = (ushort*)(ws + O_BufA);
    ushort* bufB  = (ushort*)(ws + O_BufB);
    ushort* Pb    = (ushort*)(ws + O_Pb);
    ushort* PTb   = (ushort*)(ws + O_PTb);
    ushort* Gb    = (ushort*)(ws + O_Gb);
    ushort* PtXTb = (ushort*)(ws + O_PtXTb);
    float*  ssB   = (float*)(ws + O_ssB);
    ushort* W1T   = (ushort*)(ws + O_W1T);
    float*  ssA   = (float*)(ws + O_ssA);
    float*  z     = (float*)(ws + O_scratch);
    ushort* Gpart = (ushort*)(ws + O_scratch);
    ushort* PXpart = (ushort*)d_out;
    ushort* Gsum  = PTb;                       // PTb region reuse (dead)
    ushort* PXsum = PTb + 589824;
    (void)in_sizes; (void)n_in; (void)out_size;

    const bool big = ws_size >= WS_BIG;
    const int nzg = big ? 16 : 4;
    const int nzp = big ? 32 : 8;

    prep_w1t_k<<<64, 256, 0, stream>>>(W1, W1T);
    tobf16_k<<<N_ROWS, 256, 0, stream>>>(X, bufA, ssA);

    ushort* xm  = bufA;
    ushort* alt = bufB;
    float* ssCur = ssA;
    float* ssNxt = ssB;

    for (int it = 0; it < DEPTH; ++it) {
        if (big) {
            txz_k<<<4096 + 256, 256, 0, stream>>>(xm, ssCur, alt, W1T, b1, z);
        } else {
            transpose_k<<<dim3(N_ROWS / 64, DIM / 64), 256, 0, stream>>>(xm, ssCur, alt);
            zgemm_k<<<N_ROWS / 64, 256, 0, stream>>>(xm, W1T, b1, z, ssCur);
        }
        head_k<<<N_ROWS / 256, 256, 0, stream>>>(z, W2, b2, Pb, PTb, nullptr, 1);
        if (big) {
            gp_k<<<576 + 256, 256, 0, stream>>>(alt, PTb, Gpart, PXpart);
        } else {
            gemm_nt_k<128, 128, 0, 1><<<dim3(36 * 4, 1, 1), 256, 0, stream>>>(
                alt, N_ROWS, alt, N_ROWS, 4096,
                nullptr, 0, nullptr, 0, 0,
                (float*)Gpart, 128, nullptr, 0.f, nullptr, 36 * 16384, 4);
            gemm_nt_k<128, 64, 0, 0><<<dim3(8, 1, 8), 256, 0, stream>>>(
                alt, N_ROWS, PTb, N_ROWS, 2048,
                nullptr, 0, nullptr, 0, 0,
                (float*)PXpart, OUTD, nullptr, 0.f, nullptr, DIM * OUTD, 0);
        }
        reduce_k<<<320, 256, 0, stream>>>(Gpart, PXpart, Gsum, PXsum, nzg, nzp);
        castgp_k<<<1088, 256, 0, stream>>>(Gsum, PXsum, Gb, PtXTb, ssNxt);
        // X_{t+1} = Xn + g*(P@PtX - Xn@G); writes `alt`; accumulates ssNxt
        gemm_nt_k<128, 128, 1, 0><<<dim3(N_ROWS / 128, DIM / 128, 1), 256, 0, stream>>>(
            xm, DIM, Gb, DIM, 1024,
            Pb, OUTD, PtXTb, OUTD, OUTD,
            (float*)alt, DIM, ssCur, GAMMA, ssNxt, 0, 0);
        ushort* tmp = xm; xm = alt; alt = tmp;
        float* ts2 = ssCur; ssCur = ssNxt; ssNxt = ts2;
    }

    zgemm_k<<<N_ROWS / 64, 256, 0, stream>>>(xm, W1T, b1, z, nullptr);
    head_k<<<N_ROWS / 256, 256, 0, stream>>>(z, W2, b2, Pb, PTb, out, 0);
}

// Round 8
// 973.164 us; speedup vs baseline: 1.1799x; 1.1180x over previous
//
#include <hip/hip_runtime.h>

// CKAFormer R15 (from R14; R14 post-mortem: LDS-capture epilogue REGRESSED
// EPI1 60->86.9us with WRITE 36.9->107.5MB (partial-line eviction storm from
// the unpaced scattered-store burst; mechanism not fully attributed -> revert
// per discipline). R11 (908.7us) is the proven best.
// R15 = exact R11 revert + ONE isolated change: the update gemm gets a
// DEDICATED non-template kernel upd1_k (seg0 K=1024 + seg1 K=64 hardcoded,
// no TRI/EPI/zidx branches, own regalloc context). Rationale: identical math
// ran 51.5us in R10 as a standalone template and 60us in R11 after being
// refactored into the shared gemm_body co-compiled with gp_k — rule #19
// codegen perturbation worth 51us total. gemm_body slimmed to EPI0-only
// (partial-store gemms), which also cleans gp_k's compile context.
// Everything else byte-identical to R11.

#define N_ROWS 16384
#define DIM 1024
#define HID 16
#define OUTD 64
#define DEPTH 6
#define GAMMA 1e-4f

typedef short bf16x8 __attribute__((ext_vector_type(8)));
typedef unsigned short u16x8 __attribute__((ext_vector_type(8)));
typedef float f32x4 __attribute__((ext_vector_type(4)));

#define AS1C(p) ((const __attribute__((address_space(1))) void*)(p))
#define AS3(p)  ((__attribute__((address_space(3))) void*)(p))

__device__ __forceinline__ unsigned short f2bf(float f) {
    unsigned u = __builtin_bit_cast(unsigned, f);
    u += 0x7fffu + ((u >> 16) & 1u);   // round-to-nearest-even
    return (unsigned short)(u >> 16);
}
__device__ __forceinline__ float b2f(ushort u) {
    unsigned x = ((unsigned)u) << 16;
    return __builtin_bit_cast(float, x);
}
// stored offset of logical element n within a swizzled row keyed by (row&7)
__device__ __forceinline__ int swz(int n, int row) {
    return (n & ~63) | ((((n >> 3) & 7) ^ (row & 7)) << 3) | (n & 7);
}

// ---------------------------------------------------------------------------
// Once per launch: master Xm = bf16(X) swizzled rows + ssout[row] = ||X[row]||^2.
__global__ __launch_bounds__(256) void tobf16_k(const float* __restrict__ X,
        ushort* __restrict__ Xm, float* __restrict__ ssout) {
    int row = blockIdx.x, t = threadIdx.x;
    float4 v = ((const float4*)(X + (size_t)row * DIM))[t];
    ushort4 o4;
    o4.x = f2bf(v.x); o4.y = f2bf(v.y); o4.z = f2bf(v.z); o4.w = f2bf(v.w);
    *(ushort4*)(Xm + (size_t)row * DIM + swz(t * 4, row)) = o4;
    float ss = v.x * v.x + v.y * v.y + v.z * v.z + v.w * v.w;
    for (int o = 32; o > 0; o >>= 1) ss += __shfl_down(ss, o);
    __shared__ float wsum[4];
    if ((t & 63) == 0) wsum[t >> 6] = ss;
    __syncthreads();
    if (t == 0) ssout[row] = wsum[0] + wsum[1] + wsum[2] + wsum[3];
}

// ---------------------------------------------------------------------------
// XnT[d][k] = bf16(Xm[k][d] / ||X[k]||), swizzled by d. LDS 64x65 f32 tile.
__device__ __forceinline__ void transpose_body(const ushort* __restrict__ Xm,
        const float* __restrict__ ss, ushort* __restrict__ XnT,
        int bx, int by, float* ts, float* riS) {
    int r0 = bx * 64;   // source row (k) tile
    int c0 = by * 64;   // source col (d) tile
    int t = threadIdx.x;
    if (t < 64) riS[t] = 1.0f / sqrtf(ss[r0 + t]);
    __syncthreads();
#pragma unroll
    for (int i = 0; i < 2; ++i) {
        int idx = i * 256 + t;
        int r = idx >> 3, lg = idx & 7;
        int rr = r0 + r;
        const ushort* p = Xm + (size_t)rr * DIM + c0 + ((lg ^ (rr & 7)) << 3);
        u16x8 a = *(const u16x8*)p;
        float s = riS[r];
        float* d = &ts[r * 65 + lg * 8];
#pragma unroll
        for (int u = 0; u < 8; ++u) d[u] = b2f(a[u]) * s;
    }
    __syncthreads();
#pragma unroll
    for (int i = 0; i < 2; ++i) {
        int g = i * 256 + t;
        int c = g >> 3;
        int rg = g & 7;
        u16x8 pk;
#pragma unroll
        for (int u = 0; u < 8; ++u) pk[u] = f2bf(ts[(rg * 8 + u) * 65 + c]);
        *(u16x8*)(XnT + (size_t)(c0 + c) * N_ROWS + r0 + ((rg ^ (c & 7)) << 3)) = pk;
    }
}

// ---------------------------------------------------------------------------
// z[m][h] = (Xm[m]·W1[:,h]) / ||X[m]|| + b1[h]   (ss=nullptr -> no scale; final).
__device__ __forceinline__ void zgemm_body(const ushort* __restrict__ Xm,
        const ushort* __restrict__ W1T, const float* __restrict__ b1,
        float* __restrict__ z, const float* __restrict__ ss, int bidx) {
    int t = threadIdx.x;
    int wave = t >> 6, lane = t & 63;
    int rl = lane & 15, q = lane >> 4;
    int rowbase = bidx * 64 + wave * 16;
    int m = rowbase + rl;
    int msw = m & 7;
    const ushort* arow = Xm + (size_t)m * DIM;
    const ushort* brow = W1T + (size_t)rl * DIM + q * 8;
    f32x4 acc = {0.f, 0.f, 0.f, 0.f};
#pragma unroll 8
    for (int kt = 0; kt < DIM; kt += 32) {
        int gl = ((kt >> 3) & 7) | q;
        int off = (kt & ~63) + ((gl ^ msw) << 3);
        bf16x8 a = *(const bf16x8*)(arow + off);
        bf16x8 b = *(const bf16x8*)(brow + kt);
        acc = __builtin_amdgcn_mfma_f32_16x16x32_bf16(a, b, acc, 0, 0, 0);
    }
#pragma unroll
    for (int rg = 0; rg < 4; ++rg) {
        int mm = rowbase + q * 4 + rg;
        float s = ss ? 1.0f / sqrtf(ss[mm]) : 1.0f;
        z[(size_t)mm * HID + rl] = acc[rg] * s + b1[rl];
    }
}

// ---------------------------------------------------------------------------
// Fused transpose (blocks 0..4095) + zgemm (blocks 4096..4351).
__global__ __launch_bounds__(256) void txz_k(const ushort* __restrict__ Xm,
        const float* __restrict__ ss, ushort* __restrict__ XnT,
        const ushort* __restrict__ W1T, const float* __restrict__ b1,
        float* __restrict__ z) {
    __shared__ float ts[64 * 65];
    __shared__ float riS[64];
    int bid = blockIdx.x;
    if (bid < 4096) transpose_body(Xm, ss, XnT, bid & 255, bid >> 8, ts, riS);
    else            zgemm_body(Xm, W1T, b1, z, ss, bid - 4096);
}

// standalone wrappers (small path / final)
__global__ __launch_bounds__(256) void transpose_k(const ushort* __restrict__ Xm,
        const float* __restrict__ ss, ushort* __restrict__ XnT) {
    __shared__ float ts[64 * 65];
    __shared__ float riS[64];
    transpose_body(Xm, ss, XnT, blockIdx.x, blockIdx.y, ts, riS);
}
__global__ __launch_bounds__(256) void zgemm_k(const ushort* __restrict__ Xm,
        const ushort* __restrict__ W1T, const float* __restrict__ b1,
        float* __restrict__ z, const float* __restrict__ ss) {
    zgemm_body(Xm, W1T, b1, z, ss, blockIdx.x);
}

// ---------------------------------------------------------------------------
__global__ __launch_bounds__(256) void prep_w1t_k(const float* __restrict__ W1,
        ushort* __restrict__ W1T) {
    int idx = blockIdx.x * 256 + threadIdx.x;   // 16384
    int h = idx >> 10, j = idx & 1023;
    W1T[idx] = f2bf(W1[j * HID + h]);
}

// ---------------------------------------------------------------------------
// Per row: h = relu(z); logits = h@W2 + b2; softmax -> Pb (swizzled by m&7)
// + PTb (rows o, swizzled by o&7), or (do_softmax=0) logits f32 to out.
__global__ __launch_bounds__(256) void head_k(const float* __restrict__ z,
        const float* __restrict__ W2, const float* __restrict__ b2,
        ushort* __restrict__ Pb, ushort* __restrict__ PTb,
        float* __restrict__ out, int do_softmax) {
    __shared__ float w2s[HID * OUTD];
    __shared__ float b2s[OUTD];
    int t = threadIdx.x;
    ((float4*)w2s)[t] = ((const float4*)W2)[t];
    if (t < OUTD) b2s[t] = b2[t];
    __syncthreads();
    int m = blockIdx.x * 256 + t;
    float h[HID];
    const float4* zp = (const float4*)(z + (size_t)m * HID);
#pragma unroll
    for (int i = 0; i < 4; ++i) {
        float4 v = zp[i];
        h[i * 4 + 0] = fmaxf(v.x, 0.f); h[i * 4 + 1] = fmaxf(v.y, 0.f);
        h[i * 4 + 2] = fmaxf(v.z, 0.f); h[i * 4 + 3] = fmaxf(v.w, 0.f);
    }
    float lo[OUTD];
#pragma unroll
    for (int o = 0; o < OUTD; ++o) lo[o] = b2s[o];
    for (int i = 0; i < HID; ++i) {
        float hv = h[i];
#pragma unroll
        for (int o = 0; o < OUTD; ++o) lo[o] += hv * w2s[i * OUTD + o];
    }
    if (do_softmax) {
        float mx = lo[0];
#pragma unroll
        for (int o = 1; o < OUTD; ++o) mx = fmaxf(mx, lo[o]);
        float sm = 0.f;
#pragma unroll
        for (int o = 0; o < OUTD; ++o) { float e = __expf(lo[o] - mx); lo[o] = e; sm += e; }
        float inv = 1.0f / sm;
#pragma unroll
        for (int o8 = 0; o8 < 8; ++o8) {
            u16x8 pk;
#pragma unroll
            for (int u = 0; u < 8; ++u) pk[u] = f2bf(lo[o8 * 8 + u] * inv);
            ((u16x8*)(Pb + (size_t)m * OUTD))[o8 ^ (m & 7)] = pk;
        }
#pragma unroll
        for (int o = 0; o < OUTD; ++o)
            PTb[(size_t)o * N_ROWS + swz(m, o)] = f2bf(lo[o] * inv);
    } else {
        float4* op = (float4*)(out + (size_t)m * OUTD);
#pragma unroll
        for (int o4 = 0; o4 < 16; ++o4) {
            float4 v; v.x = lo[o4 * 4 + 0]; v.y = lo[o4 * 4 + 1];
            v.z = lo[o4 * 4 + 2]; v.w = lo[o4 * 4 + 3];
            op[o4] = v;
        }
    }
}

// ---------------------------------------------------------------------------
// Pass A: coalesced split-K reduction -> compact bf16 sums.
__global__ __launch_bounds__(256) void reduce_k(const ushort* __restrict__ Gp,
        const ushort* __restrict__ PXp, ushort* __restrict__ Gsum,
        ushort* __restrict__ PXsum, int nzg, int nzp) {
    int idx = blockIdx.x * 256 + threadIdx.x;   // 81920 units of 8 elems
    if (idx < 73728) {
        size_t off = (size_t)idx * 8;
        float acc[8] = {0.f, 0.f, 0.f, 0.f, 0.f, 0.f, 0.f, 0.f};
        for (int zz = 0; zz < nzg; ++zz) {
            u16x8 v = *(const u16x8*)(Gp + (size_t)zz * 589824 + off);
#pragma unroll
            for (int u = 0; u < 8; ++u) acc[u] += b2f(v[u]);
        }
        u16x8 o;
#pragma unroll
        for (int u = 0; u < 8; ++u) o[u] = f2bf(acc[u]);
        *(u16x8*)(Gsum + off) = o;
    } else {
        size_t off = (size_t)(idx - 73728) * 8;
        float acc[8] = {0.f, 0.f, 0.f, 0.f, 0.f, 0.f, 0.f, 0.f};
        for (int zz = 0; zz < nzp; ++zz) {
            u16x8 v = *(const u16x8*)(PXp + (size_t)zz * 65536 + off);
#pragma unroll
            for (int u = 0; u < 8; ++u) acc[u] += b2f(v[u]);
        }
        u16x8 o;
#pragma unroll
        for (int u = 0; u < 8; ++u) o[u] = f2bf(acc[u]);
        *(u16x8*)(PXsum + off) = o;
    }
}

// ---------------------------------------------------------------------------
// Pass B: gather/mirror/swizzle of the L2-resident sums + zero next ssacc.
__global__ __launch_bounds__(256) void castgp_k(const ushort* __restrict__ Gsum,
        const ushort* __restrict__ PXsum, ushort* __restrict__ Gb,
        ushort* __restrict__ PtXTb, float* __restrict__ ssz) {
    if (blockIdx.x < 64) ssz[blockIdx.x * 256 + threadIdx.x] = 0.f;
    int idx = blockIdx.x * 256 + threadIdx.x;   // 278528 units
    if (idx < 262144) {
        int n = idx >> 8;
        int so = (idx & 255) * 4;
        int k0 = (so & ~63) | ((((so >> 3) & 7) ^ (n & 7)) << 3) | (so & 7);
        ushort po[4];
#pragma unroll
        for (int u = 0; u < 4; ++u) {
            int kk = k0 + u;
            int a = min(n, kk), b = max(n, kk);
            int tm = a >> 7, tn = b >> 7;
            int tlin = tm * 8 - ((tm * (tm - 1)) >> 1) + (tn - tm);
            size_t off = (size_t)tlin * 16384 + (size_t)(a & 127) * 128 + (b & 127);
            po[u] = (ushort)(Gsum[off] ^ 0x8000u);   // negate via sign bit
        }
        ushort4 o; o.x = po[0]; o.y = po[1]; o.z = po[2]; o.w = po[3];
        *(ushort4*)(Gb + (size_t)n * DIM + so) = o;
    } else {
        int vv = idx - 262144;                  // 16384 units
        int d = vv >> 4;
        int so = (vv & 15) * 4;
        int k0 = ((((so >> 3) & 7) ^ (d & 7)) << 3) | (so & 7);
        const ushort* src = PXsum + (size_t)d * OUTD + k0;
        ushort4 o; o.x = src[0]; o.y = src[1]; o.z = src[2]; o.w = src[3];
        *(ushort4*)(PtXTb + (size_t)d * OUTD + so) = o;
    }
}

// ---------------------------------------------------------------------------
// Partial-store NT MFMA GEMM body (R5-proven loop; EPI0 only).
template<int BM, int BN, int TRI>
__device__ __forceinline__ void gemm0_body(
        const ushort* __restrict__ A0, int lda0,
        const ushort* __restrict__ B0, int ldb0, int k0len,
        ushort* __restrict__ C, int pstride, int nz,
        int bx, int by, int bz, ushort* ls) {
    constexpr int WTN = BN / 2;
    constexpr int NF = WTN / 16;
    constexpr int NAW = BM / 64;     // waves staging A
    constexpr int NBW = BN / 64;     // waves staging B
    ushort* lsA = ls;
    ushort* lsB = ls + BM * 64;
    int t = threadIdx.x;
    int wave = t >> 6, lane = t & 63;
    int rl = lane & 15, q = lane >> 4;
    int wm = wave & 1, wn = wave >> 1;
    int m0, n0, zidx, tlin = 0;
    if (TRI) {
        int bid = bx;
        int bxx, tm = 0;
        if (nz == 16) {                 // R7-proven mapping: grid 8*36*2
            int rest = bid >> 3;
            bxx = rest % 36;
            int zhi = rest / 36;
            zidx = (bid & 7) | (zhi << 3);
        } else {                        // fallback: grid 36*4
            zidx = bid & 3;
            bxx = bid >> 2;
        }
        tlin = bxx;
        while (bxx >= 8 - tm) { bxx -= 8 - tm; ++tm; }
        m0 = tm * 128; n0 = (tm + bxx) * 128;
    } else {
        m0 = bx * BM; n0 = by * BN; zidx = bz;
    }
    int lrow8 = lane >> 3, lgrp = lane & 7;
    bool isA = wave < NAW;
    bool active = wave < NAW + NBW;
    int wlocal = isA ? wave : wave - NAW;
    ushort* dstb = ls + (isA ? 0 : BM * 64) + wlocal * 4096;

    f32x4 acc[4][NF];
#pragma unroll
    for (int i = 0; i < 4; ++i)
#pragma unroll
        for (int j = 0; j < NF; ++j) acc[i][j] = f32x4{0.f, 0.f, 0.f, 0.f};

    const ushort* srcb;
    size_t ldS;
    if (isA) {
        srcb = A0 + (size_t)(m0 + wlocal * 64 + lrow8) * lda0 + lgrp * 8;
        ldS = (size_t)lda0;
    } else {
        srcb = B0 + (size_t)(n0 + wlocal * 64 + lrow8) * ldb0 + lgrp * 8;
        ldS = (size_t)ldb0;
    }
    srcb += zidx * k0len;
    for (int kt = 0; kt < k0len; kt += 64) {
        if (active) {
#pragma unroll
            for (int c = 0; c < 8; ++c)
                __builtin_amdgcn_global_load_lds(AS1C(srcb + c * 8 * ldS),
                                                 AS3(dstb + c * 512), 16, 0, 0);
            srcb += 64;
        }
        __syncthreads();
#pragma unroll
        for (int s = 0; s < 2; ++s) {
            bf16x8 af[4], bfr[NF];
#pragma unroll
            for (int i = 0; i < 4; ++i) {
                int row = wm * 64 + i * 16 + rl;
                int sg = ((s << 2) | q) ^ (row & 7);
                af[i] = *(const bf16x8*)&lsA[row * 64 + sg * 8];
            }
#pragma unroll
            for (int j = 0; j < NF; ++j) {
                int row = wn * WTN + j * 16 + rl;
                int sg = ((s << 2) | q) ^ (row & 7);
                bfr[j] = *(const bf16x8*)&lsB[row * 64 + sg * 8];
            }
#pragma unroll
            for (int i = 0; i < 4; ++i)
#pragma unroll
                for (int j = 0; j < NF; ++j)
                    acc[i][j] = __builtin_amdgcn_mfma_f32_16x16x32_bf16(
                        af[i], bfr[j], acc[i][j], 0, 0, 0);
        }
        __syncthreads();
    }

    // plain bf16 pair stores into this z-slice's partial buffer
    ushort* Cb = C + (size_t)zidx * (size_t)pstride;
#pragma unroll
    for (int i = 0; i < 4; ++i)
#pragma unroll
        for (int j = 0; j < NF; ++j)
#pragma unroll
            for (int rg = 0; rg < 4; ++rg) {
                float v = acc[i][j][rg];
                float vp = __shfl_xor(v, 1);   // partner lane's (n^1) value
                if ((rl & 1) == 0) {
                    int ml = wm * 64 + i * 16 + q * 4 + rg;
                    int nl = wn * WTN + j * 16 + rl;
                    size_t off;
                    if (TRI)
                        off = (size_t)tlin * (BM * BN) + (size_t)ml * BN + nl;
                    else
                        off = (size_t)(m0 + ml) * 0 + (size_t)(m0 + ml) * OUTD + nl; // non-TRI: ldc=OUTD
                    unsigned pk = (unsigned)f2bf(v) | ((unsigned)f2bf(vp) << 16);
                    *(unsigned*)(Cb + off) = pk;
                }
            }
}

template<int BM, int BN, int TRI>
__global__ __launch_bounds__(256, 3) void gemm_nt_k(
        const ushort* __restrict__ A0, int lda0,
        const ushort* __restrict__ B0, int ldb0, int k0len,
        ushort* __restrict__ C, int pstride, int nz) {
    __shared__ ushort ls[(BM + BN) * 64];
    gemm0_body<BM, BN, TRI>(A0, lda0, B0, ldb0, k0len, C, pstride, nz,
        blockIdx.x, blockIdx.y, blockIdx.z, ls);
}

// ---------------------------------------------------------------------------
// Fused G-gemm (blocks 0..575, TRI split-K 16) + PtX-gemm (576..831, split-K 32).
__global__ __launch_bounds__(256, 3) void gp_k(const ushort* __restrict__ XnT,
        const ushort* __restrict__ PTb, ushort* __restrict__ Gpart,
        ushort* __restrict__ PXpart) {
    __shared__ ushort ls[256 * 64];
    int bid = blockIdx.x;
    if (bid < 576) {
        gemm0_body<128, 128, 1>(XnT, N_ROWS, XnT, N_ROWS, 1024,
            Gpart, 36 * 16384, 16, bid, 0, 0, ls);
    } else {
        int b2 = bid - 576;
        gemm0_body<128, 64, 0>(XnT, N_ROWS, PTb, N_ROWS, 512,
            PXpart, DIM * OUTD, 0, b2 & 7, 0, b2 >> 3, ls);
    }
}

// ---------------------------------------------------------------------------
// R15 dedicated update gemm: X_{t+1} = Xn + g*(P@PtX - Xn@G).
// Standalone kernel, own regalloc context (R10's 51.5us codegen target).
// seg0: Xm(ld DIM) @ Gb(ld DIM)^T, K=1024. rvv scale. seg1: Pb @ PtXTb
// (ld OUTD), K=64. Epilogue: vf = base*rinv + gamma*acc -> bf16 master +
// row sum-of-squares atomics. Math order identical to R11's EPI1.
__global__ __launch_bounds__(256, 3) void upd1_k(
        const ushort* __restrict__ Xm, const ushort* __restrict__ Gb,
        const ushort* __restrict__ Pb, const ushort* __restrict__ PtXTb,
        ushort* __restrict__ Cm, const float* __restrict__ ssrd,
        float gamma, float* __restrict__ ssacc) {
    __shared__ ushort ls[256 * 64];
    ushort* lsA = ls;
    ushort* lsB = ls + 128 * 64;
    int t = threadIdx.x;
    int wave = t >> 6, lane = t & 63;
    int rl = lane & 15, q = lane >> 4;
    int wm = wave & 1, wn = wave >> 1;
    int m0 = blockIdx.x * 128, n0 = blockIdx.y * 128;
    int lrow8 = lane >> 3, lgrp = lane & 7;
    bool isA = wave < 2;
    int wlocal = isA ? wave : wave - 2;
    ushort* dstb = ls + (isA ? 0 : 8192) + wlocal * 4096;

    f32x4 acc[4][4];
#pragma unroll
    for (int i = 0; i < 4; ++i)
#pragma unroll
        for (int j = 0; j < 4; ++j) acc[i][j] = f32x4{0.f, 0.f, 0.f, 0.f};

    // seg0: K=1024
    {
        const ushort* srcb = isA
            ? Xm + (size_t)(m0 + wlocal * 64 + lrow8) * DIM + lgrp * 8
            : Gb + (size_t)(n0 + wlocal * 64 + lrow8) * DIM + lgrp * 8;
        for (int kt = 0; kt < 1024; kt += 64) {
#pragma unroll
            for (int c = 0; c < 8; ++c)
                __builtin_amdgcn_global_load_lds(AS1C(srcb + c * 8 * DIM),
                                                 AS3(dstb + c * 512), 16, 0, 0);
            srcb += 64;
            __syncthreads();
#pragma unroll
            for (int s = 0; s < 2; ++s) {
                bf16x8 af[4], bfr[4];
#pragma unroll
                for (int i = 0; i < 4; ++i) {
                    int row = wm * 64 + i * 16 + rl;
                    int sg = ((s << 2) | q) ^ (row & 7);
                    af[i] = *(const bf16x8*)&lsA[row * 64 + sg * 8];
                }
#pragma unroll
                for (int j = 0; j < 4; ++j) {
                    int row = wn * 64 + j * 16 + rl;
                    int sg = ((s << 2) | q) ^ (row & 7);
                    bfr[j] = *(const bf16x8*)&lsB[row * 64 + sg * 8];
                }
#pragma unroll
                for (int i = 0; i < 4; ++i)
#pragma unroll
                    for (int j = 0; j < 4; ++j)
                        acc[i][j] = __builtin_amdgcn_mfma_f32_16x16x32_bf16(
                            af[i], bfr[j], acc[i][j], 0, 0, 0);
            }
            __syncthreads();
        }
    }

    // rvv scale (Xn@G needs rinv[m])
    float rvv[4][4];
#pragma unroll
    for (int i = 0; i < 4; ++i)
#pragma unroll
        for (int rg = 0; rg < 4; ++rg) {
            rvv[i][rg] = 1.0f / sqrtf(ssrd[m0 + wm * 64 + i * 16 + q * 4 + rg]);
#pragma unroll
            for (int j = 0; j < 4; ++j) acc[i][j][rg] *= rvv[i][rg];
        }

    // seg1: K=64
    {
        const ushort* srcb = isA
            ? Pb + (size_t)(m0 + wlocal * 64 + lrow8) * OUTD + lgrp * 8
            : PtXTb + (size_t)(n0 + wlocal * 64 + lrow8) * OUTD + lgrp * 8;
#pragma unroll
        for (int c = 0; c < 8; ++c)
            __builtin_amdgcn_global_load_lds(AS1C(srcb + c * 8 * OUTD),
                                             AS3(dstb + c * 512), 16, 0, 0);
        __syncthreads();
#pragma unroll
        for (int s = 0; s < 2; ++s) {
            bf16x8 af[4], bfr[4];
#pragma unroll
            for (int i = 0; i < 4; ++i) {
                int row = wm * 64 + i * 16 + rl;
                int sg = ((s << 2) | q) ^ (row & 7);
                af[i] = *(const bf16x8*)&lsA[row * 64 + sg * 8];
            }
#pragma unroll
            for (int j = 0; j < 4; ++j) {
                int row = wn * 64 + j * 16 + rl;
                int sg = ((s << 2) | q) ^ (row & 7);
                bfr[j] = *(const bf16x8*)&lsB[row * 64 + sg * 8];
            }
#pragma unroll
            for (int i = 0; i < 4; ++i)
#pragma unroll
                for (int j = 0; j < 4; ++j)
                    acc[i][j] = __builtin_amdgcn_mfma_f32_16x16x32_bf16(
                        af[i], bfr[j], acc[i][j], 0, 0, 0);
        }
    }

    // epilogue: vf = base*rinv + gamma*acc; bf16 master write + ss atomics.
#pragma unroll
    for (int i = 0; i < 4; ++i)
#pragma unroll
        for (int rg = 0; rg < 4; ++rg) {
            int m = m0 + wm * 64 + i * 16 + q * 4 + rg;
            float ssl = 0.f;
#pragma unroll
            for (int j = 0; j < 4; ++j) {
                int n = n0 + wn * 64 + j * 16 + rl;
                int so = swz(n, m);
                float base = b2f(Xm[(size_t)m * DIM + so]);
                float vf = base * rvv[i][rg] + gamma * acc[i][j][rg];
                Cm[(size_t)m * DIM + so] = f2bf(vf);
                ssl += vf * vf;
            }
            ssl += __shfl_xor(ssl, 1);
            ssl += __shfl_xor(ssl, 2);
            ssl += __shfl_xor(ssl, 4);
            ssl += __shfl_xor(ssl, 8);
            if (rl == 0) atomicAdd(&ssacc[m], ssl);
        }
}

// ---------------------------------------------------------------------------
extern "C" void kernel_launch(void* const* d_in, const int* in_sizes, int n_in,
                              void* d_out, int out_size, void* d_ws, size_t ws_size,
                              hipStream_t stream) {
    const float* X = (const float*)d_in[0];
    const float* W1 = (const float*)d_in[1];
    const float* b1 = (const float*)d_in[2];
    const float* W2 = (const float*)d_in[3];
    const float* b2 = (const float*)d_in[4];
    float* out = (float*)d_out;
    char* ws = (char*)d_ws;

    constexpr size_t O_BufA    = 0;                                     // 33,554,432
    constexpr size_t O_BufB    = O_BufA + (size_t)N_ROWS * DIM * 2;     // 33,554,432
    constexpr size_t O_Pb      = O_BufB + (size_t)N_ROWS * DIM * 2;     //  2,097,152
    constexpr size_t O_PTb     = O_Pb + (size_t)N_ROWS * OUTD * 2;      //  2,097,152
    constexpr size_t O_Gb      = O_PTb + (size_t)OUTD * N_ROWS * 2;     //  2,097,152
    constexpr size_t O_PtXTb   = O_Gb + (size_t)DIM * DIM * 2;          //    131,072
    constexpr size_t O_ssB     = O_PtXTb + (size_t)DIM * OUTD * 2;      //     65,536
    constexpr size_t O_W1T     = O_ssB + (size_t)N_ROWS * 4;            //     32,768
    constexpr size_t O_ssA     = O_W1T + (size_t)HID * DIM * 2;         //     65,536
    constexpr size_t O_scratch = O_ssA + (size_t)N_ROWS * 4;            // = 73,695,232
    constexpr size_t WS_BIG = O_scratch + (size_t)16 * 589824 * 2;

    ushort* bufA  = (ushort*)(ws + O_BufA);
    ushort* bufB  = (ushort*)(ws + O_BufB);
    ushort* Pb    = (ushort*)(ws + O_Pb);
    ushort* PTb   = (ushort*)(ws + O_PTb);
    ushort* Gb    = (ushort*)(ws + O_Gb);
    ushort* PtXTb = (ushort*)(ws + O_PtXTb);
    float*  ssB   = (float*)(ws + O_ssB);
    ushort* W1T   = (ushort*)(ws + O_W1T);
    float*  ssA   = (float*)(ws + O_ssA);
    float*  z     = (float*)(ws + O_scratch);
    ushort* Gpart = (ushort*)(ws + O_scratch);
    ushort* PXpart = (ushort*)d_out;
    ushort* Gsum  = PTb;                       // PTb region reuse (dead)
    ushort* PXsum = PTb + 589824;
    (void)in_sizes; (void)n_in; (void)out_size;

    const bool big = ws_size >= WS_BIG;
    const int nzg = big ? 16 : 4;
    const int nzp = big ? 32 : 8;

    prep_w1t_k<<<64, 256, 0, stream>>>(W1, W1T);
    tobf16_k<<<N_ROWS, 256, 0, stream>>>(X, bufA, ssA);

    ushort* xm  = bufA;
    ushort* alt = bufB;
    float* ssCur = ssA;
    float* ssNxt = ssB;

    for (int it = 0; it < DEPTH; ++it) {
        if (big) {
            txz_k<<<4096 + 256, 256, 0, stream>>>(xm, ssCur, alt, W1T, b1, z);
        } else {
            transpose_k<<<dim3(N_ROWS / 64, DIM / 64), 256, 0, stream>>>(xm, ssCur, alt);
            zgemm_k<<<N_ROWS / 64, 256, 0, stream>>>(xm, W1T, b1, z, ssCur);
        }
        head_k<<<N_ROWS / 256, 256, 0, stream>>>(z, W2, b2, Pb, PTb, nullptr, 1);
        if (big) {
            gp_k<<<576 + 256, 256, 0, stream>>>(alt, PTb, Gpart, PXpart);
        } else {
            gemm_nt_k<128, 128, 1><<<dim3(36 * 4, 1, 1), 256, 0, stream>>>(
                alt, N_ROWS, alt, N_ROWS, 4096, Gpart, 36 * 16384, 4);
            gemm_nt_k<128, 64, 0><<<dim3(8, 1, 8), 256, 0, stream>>>(
                alt, N_ROWS, PTb, N_ROWS, 2048, PXpart, DIM * OUTD, 0);
        }
        reduce_k<<<320, 256, 0, stream>>>(Gpart, PXpart, Gsum, PXsum, nzg, nzp);
        castgp_k<<<1088, 256, 0, stream>>>(Gsum, PXsum, Gb, PtXTb, ssNxt);
        // X_{t+1} = Xn + g*(P@PtX - Xn@G); dedicated kernel
        upd1_k<<<dim3(N_ROWS / 128, DIM / 128, 1), 256, 0, stream>>>(
            xm, Gb, Pb, PtXTb, alt, ssCur, GAMMA, ssNxt);
        ushort* tmp = xm; xm = alt; alt = tmp;
        float* ts2 = ssCur; ssCur = ssNxt; ssNxt = ts2;
    }

    zgemm_k<<<N_ROWS / 64, 256, 0, stream>>>(xm, W1T, b1, z, nullptr);
    head_k<<<N_ROWS / 256, 256, 0, stream>>>(z, W2, b2, Pb, PTb, out, 0);
}

// Round 9
// 907.515 us; speedup vs baseline: 1.2653x; 1.0723x over previous
//
#include <hip/hip_runtime.h>

// CKAFormer R16 (from R15; R15 post-mortem: dedicated upd1_k = 62-63us, same
// as shared-template R11 -> codegen-perturbation theory DEAD; R10's 51.5 was
// machine-state noise (rule #13). upd1 counters: MfmaUtil 22%, HBM 18%,
// VALUBusy 23% — barrier/latency-bound, nothing saturated.
// R16 = single-variable change: __launch_bounds__(256,3) -> (256,4) on the
// three gemm kernels. Derivation: VGPR is now 60-68 (<<128 cap for 4
// waves/SIMD; the (256,3) was R5 legacy from a 164-VGPR era) and LDS 32KB
// (4x32=128 <= 160KB). Gains: (a) TAIL QUANTIZATION — upd1 grid 1024 = 4x256
// exact single round (was 768 + 256-block 1/3-fill second round); gp_k 832
// <= 1024 single round (was 768+64 tail); (b) 4th independent block/CU gives
// the SIMD scheduler a runnable wave during each block's vmcnt(0) barrier
// drain (the known ~20% stall of this structure).
// Everything else byte-identical to R15.

#define N_ROWS 16384
#define DIM 1024
#define HID 16
#define OUTD 64
#define DEPTH 6
#define GAMMA 1e-4f

typedef short bf16x8 __attribute__((ext_vector_type(8)));
typedef unsigned short u16x8 __attribute__((ext_vector_type(8)));
typedef float f32x4 __attribute__((ext_vector_type(4)));

#define AS1C(p) ((const __attribute__((address_space(1))) void*)(p))
#define AS3(p)  ((__attribute__((address_space(3))) void*)(p))

__device__ __forceinline__ unsigned short f2bf(float f) {
    unsigned u = __builtin_bit_cast(unsigned, f);
    u += 0x7fffu + ((u >> 16) & 1u);   // round-to-nearest-even
    return (unsigned short)(u >> 16);
}
__device__ __forceinline__ float b2f(ushort u) {
    unsigned x = ((unsigned)u) << 16;
    return __builtin_bit_cast(float, x);
}
// stored offset of logical element n within a swizzled row keyed by (row&7)
__device__ __forceinline__ int swz(int n, int row) {
    return (n & ~63) | ((((n >> 3) & 7) ^ (row & 7)) << 3) | (n & 7);
}

// ---------------------------------------------------------------------------
// Once per launch: master Xm = bf16(X) swizzled rows + ssout[row] = ||X[row]||^2.
__global__ __launch_bounds__(256) void tobf16_k(const float* __restrict__ X,
        ushort* __restrict__ Xm, float* __restrict__ ssout) {
    int row = blockIdx.x, t = threadIdx.x;
    float4 v = ((const float4*)(X + (size_t)row * DIM))[t];
    ushort4 o4;
    o4.x = f2bf(v.x); o4.y = f2bf(v.y); o4.z = f2bf(v.z); o4.w = f2bf(v.w);
    *(ushort4*)(Xm + (size_t)row * DIM + swz(t * 4, row)) = o4;
    float ss = v.x * v.x + v.y * v.y + v.z * v.z + v.w * v.w;
    for (int o = 32; o > 0; o >>= 1) ss += __shfl_down(ss, o);
    __shared__ float wsum[4];
    if ((t & 63) == 0) wsum[t >> 6] = ss;
    __syncthreads();
    if (t == 0) ssout[row] = wsum[0] + wsum[1] + wsum[2] + wsum[3];
}

// ---------------------------------------------------------------------------
// XnT[d][k] = bf16(Xm[k][d] / ||X[k]||), swizzled by d. LDS 64x65 f32 tile.
__device__ __forceinline__ void transpose_body(const ushort* __restrict__ Xm,
        const float* __restrict__ ss, ushort* __restrict__ XnT,
        int bx, int by, float* ts, float* riS) {
    int r0 = bx * 64;   // source row (k) tile
    int c0 = by * 64;   // source col (d) tile
    int t = threadIdx.x;
    if (t < 64) riS[t] = 1.0f / sqrtf(ss[r0 + t]);
    __syncthreads();
#pragma unroll
    for (int i = 0; i < 2; ++i) {
        int idx = i * 256 + t;
        int r = idx >> 3, lg = idx & 7;
        int rr = r0 + r;
        const ushort* p = Xm + (size_t)rr * DIM + c0 + ((lg ^ (rr & 7)) << 3);
        u16x8 a = *(const u16x8*)p;
        float s = riS[r];
        float* d = &ts[r * 65 + lg * 8];
#pragma unroll
        for (int u = 0; u < 8; ++u) d[u] = b2f(a[u]) * s;
    }
    __syncthreads();
#pragma unroll
    for (int i = 0; i < 2; ++i) {
        int g = i * 256 + t;
        int c = g >> 3;
        int rg = g & 7;
        u16x8 pk;
#pragma unroll
        for (int u = 0; u < 8; ++u) pk[u] = f2bf(ts[(rg * 8 + u) * 65 + c]);
        *(u16x8*)(XnT + (size_t)(c0 + c) * N_ROWS + r0 + ((rg ^ (c & 7)) << 3)) = pk;
    }
}

// ---------------------------------------------------------------------------
// z[m][h] = (Xm[m]·W1[:,h]) / ||X[m]|| + b1[h]   (ss=nullptr -> no scale; final).
__device__ __forceinline__ void zgemm_body(const ushort* __restrict__ Xm,
        const ushort* __restrict__ W1T, const float* __restrict__ b1,
        float* __restrict__ z, const float* __restrict__ ss, int bidx) {
    int t = threadIdx.x;
    int wave = t >> 6, lane = t & 63;
    int rl = lane & 15, q = lane >> 4;
    int rowbase = bidx * 64 + wave * 16;
    int m = rowbase + rl;
    int msw = m & 7;
    const ushort* arow = Xm + (size_t)m * DIM;
    const ushort* brow = W1T + (size_t)rl * DIM + q * 8;
    f32x4 acc = {0.f, 0.f, 0.f, 0.f};
#pragma unroll 8
    for (int kt = 0; kt < DIM; kt += 32) {
        int gl = ((kt >> 3) & 7) | q;
        int off = (kt & ~63) + ((gl ^ msw) << 3);
        bf16x8 a = *(const bf16x8*)(arow + off);
        bf16x8 b = *(const bf16x8*)(brow + kt);
        acc = __builtin_amdgcn_mfma_f32_16x16x32_bf16(a, b, acc, 0, 0, 0);
    }
#pragma unroll
    for (int rg = 0; rg < 4; ++rg) {
        int mm = rowbase + q * 4 + rg;
        float s = ss ? 1.0f / sqrtf(ss[mm]) : 1.0f;
        z[(size_t)mm * HID + rl] = acc[rg] * s + b1[rl];
    }
}

// ---------------------------------------------------------------------------
// Fused transpose (blocks 0..4095) + zgemm (blocks 4096..4351).
__global__ __launch_bounds__(256) void txz_k(const ushort* __restrict__ Xm,
        const float* __restrict__ ss, ushort* __restrict__ XnT,
        const ushort* __restrict__ W1T, const float* __restrict__ b1,
        float* __restrict__ z) {
    __shared__ float ts[64 * 65];
    __shared__ float riS[64];
    int bid = blockIdx.x;
    if (bid < 4096) transpose_body(Xm, ss, XnT, bid & 255, bid >> 8, ts, riS);
    else            zgemm_body(Xm, W1T, b1, z, ss, bid - 4096);
}

// standalone wrappers (small path / final)
__global__ __launch_bounds__(256) void transpose_k(const ushort* __restrict__ Xm,
        const float* __restrict__ ss, ushort* __restrict__ XnT) {
    __shared__ float ts[64 * 65];
    __shared__ float riS[64];
    transpose_body(Xm, ss, XnT, blockIdx.x, blockIdx.y, ts, riS);
}
__global__ __launch_bounds__(256) void zgemm_k(const ushort* __restrict__ Xm,
        const ushort* __restrict__ W1T, const float* __restrict__ b1,
        float* __restrict__ z, const float* __restrict__ ss) {
    zgemm_body(Xm, W1T, b1, z, ss, blockIdx.x);
}

// ---------------------------------------------------------------------------
__global__ __launch_bounds__(256) void prep_w1t_k(const float* __restrict__ W1,
        ushort* __restrict__ W1T) {
    int idx = blockIdx.x * 256 + threadIdx.x;   // 16384
    int h = idx >> 10, j = idx & 1023;
    W1T[idx] = f2bf(W1[j * HID + h]);
}

// ---------------------------------------------------------------------------
// Per row: h = relu(z); logits = h@W2 + b2; softmax -> Pb (swizzled by m&7)
// + PTb (rows o, swizzled by o&7), or (do_softmax=0) logits f32 to out.
__global__ __launch_bounds__(256) void head_k(const float* __restrict__ z,
        const float* __restrict__ W2, const float* __restrict__ b2,
        ushort* __restrict__ Pb, ushort* __restrict__ PTb,
        float* __restrict__ out, int do_softmax) {
    __shared__ float w2s[HID * OUTD];
    __shared__ float b2s[OUTD];
    int t = threadIdx.x;
    ((float4*)w2s)[t] = ((const float4*)W2)[t];
    if (t < OUTD) b2s[t] = b2[t];
    __syncthreads();
    int m = blockIdx.x * 256 + t;
    float h[HID];
    const float4* zp = (const float4*)(z + (size_t)m * HID);
#pragma unroll
    for (int i = 0; i < 4; ++i) {
        float4 v = zp[i];
        h[i * 4 + 0] = fmaxf(v.x, 0.f); h[i * 4 + 1] = fmaxf(v.y, 0.f);
        h[i * 4 + 2] = fmaxf(v.z, 0.f); h[i * 4 + 3] = fmaxf(v.w, 0.f);
    }
    float lo[OUTD];
#pragma unroll
    for (int o = 0; o < OUTD; ++o) lo[o] = b2s[o];
    for (int i = 0; i < HID; ++i) {
        float hv = h[i];
#pragma unroll
        for (int o = 0; o < OUTD; ++o) lo[o] += hv * w2s[i * OUTD + o];
    }
    if (do_softmax) {
        float mx = lo[0];
#pragma unroll
        for (int o = 1; o < OUTD; ++o) mx = fmaxf(mx, lo[o]);
        float sm = 0.f;
#pragma unroll
        for (int o = 0; o < OUTD; ++o) { float e = __expf(lo[o] - mx); lo[o] = e; sm += e; }
        float inv = 1.0f / sm;
#pragma unroll
        for (int o8 = 0; o8 < 8; ++o8) {
            u16x8 pk;
#pragma unroll
            for (int u = 0; u < 8; ++u) pk[u] = f2bf(lo[o8 * 8 + u] * inv);
            ((u16x8*)(Pb + (size_t)m * OUTD))[o8 ^ (m & 7)] = pk;
        }
#pragma unroll
        for (int o = 0; o < OUTD; ++o)
            PTb[(size_t)o * N_ROWS + swz(m, o)] = f2bf(lo[o] * inv);
    } else {
        float4* op = (float4*)(out + (size_t)m * OUTD);
#pragma unroll
        for (int o4 = 0; o4 < 16; ++o4) {
            float4 v; v.x = lo[o4 * 4 + 0]; v.y = lo[o4 * 4 + 1];
            v.z = lo[o4 * 4 + 2]; v.w = lo[o4 * 4 + 3];
            op[o4] = v;
        }
    }
}

// ---------------------------------------------------------------------------
// Pass A: coalesced split-K reduction -> compact bf16 sums.
__global__ __launch_bounds__(256) void reduce_k(const ushort* __restrict__ Gp,
        const ushort* __restrict__ PXp, ushort* __restrict__ Gsum,
        ushort* __restrict__ PXsum, int nzg, int nzp) {
    int idx = blockIdx.x * 256 + threadIdx.x;   // 81920 units of 8 elems
    if (idx < 73728) {
        size_t off = (size_t)idx * 8;
        float acc[8] = {0.f, 0.f, 0.f, 0.f, 0.f, 0.f, 0.f, 0.f};
        for (int zz = 0; zz < nzg; ++zz) {
            u16x8 v = *(const u16x8*)(Gp + (size_t)zz * 589824 + off);
#pragma unroll
            for (int u = 0; u < 8; ++u) acc[u] += b2f(v[u]);
        }
        u16x8 o;
#pragma unroll
        for (int u = 0; u < 8; ++u) o[u] = f2bf(acc[u]);
        *(u16x8*)(Gsum + off) = o;
    } else {
        size_t off = (size_t)(idx - 73728) * 8;
        float acc[8] = {0.f, 0.f, 0.f, 0.f, 0.f, 0.f, 0.f, 0.f};
        for (int zz = 0; zz < nzp; ++zz) {
            u16x8 v = *(const u16x8*)(PXp + (size_t)zz * 65536 + off);
#pragma unroll
            for (int u = 0; u < 8; ++u) acc[u] += b2f(v[u]);
        }
        u16x8 o;
#pragma unroll
        for (int u = 0; u < 8; ++u) o[u] = f2bf(acc[u]);
        *(u16x8*)(PXsum + off) = o;
    }
}

// ---------------------------------------------------------------------------
// Pass B: gather/mirror/swizzle of the L2-resident sums + zero next ssacc.
__global__ __launch_bounds__(256) void castgp_k(const ushort* __restrict__ Gsum,
        const ushort* __restrict__ PXsum, ushort* __restrict__ Gb,
        ushort* __restrict__ PtXTb, float* __restrict__ ssz) {
    if (blockIdx.x < 64) ssz[blockIdx.x * 256 + threadIdx.x] = 0.f;
    int idx = blockIdx.x * 256 + threadIdx.x;   // 278528 units
    if (idx < 262144) {
        int n = idx >> 8;
        int so = (idx & 255) * 4;
        int k0 = (so & ~63) | ((((so >> 3) & 7) ^ (n & 7)) << 3) | (so & 7);
        ushort po[4];
#pragma unroll
        for (int u = 0; u < 4; ++u) {
            int kk = k0 + u;
            int a = min(n, kk), b = max(n, kk);
            int tm = a >> 7, tn = b >> 7;
            int tlin = tm * 8 - ((tm * (tm - 1)) >> 1) + (tn - tm);
            size_t off = (size_t)tlin * 16384 + (size_t)(a & 127) * 128 + (b & 127);
            po[u] = (ushort)(Gsum[off] ^ 0x8000u);   // negate via sign bit
        }
        ushort4 o; o.x = po[0]; o.y = po[1]; o.z = po[2]; o.w = po[3];
        *(ushort4*)(Gb + (size_t)n * DIM + so) = o;
    } else {
        int vv = idx - 262144;                  // 16384 units
        int d = vv >> 4;
        int so = (vv & 15) * 4;
        int k0 = ((((so >> 3) & 7) ^ (d & 7)) << 3) | (so & 7);
        const ushort* src = PXsum + (size_t)d * OUTD + k0;
        ushort4 o; o.x = src[0]; o.y = src[1]; o.z = src[2]; o.w = src[3];
        *(ushort4*)(PtXTb + (size_t)d * OUTD + so) = o;
    }
}

// ---------------------------------------------------------------------------
// Partial-store NT MFMA GEMM body (R5-proven loop; EPI0 only).
template<int BM, int BN, int TRI>
__device__ __forceinline__ void gemm0_body(
        const ushort* __restrict__ A0, int lda0,
        const ushort* __restrict__ B0, int ldb0, int k0len,
        ushort* __restrict__ C, int pstride, int nz,
        int bx, int by, int bz, ushort* ls) {
    constexpr int WTN = BN / 2;
    constexpr int NF = WTN / 16;
    constexpr int NAW = BM / 64;     // waves staging A
    constexpr int NBW = BN / 64;     // waves staging B
    ushort* lsA = ls;
    ushort* lsB = ls + BM * 64;
    int t = threadIdx.x;
    int wave = t >> 6, lane = t & 63;
    int rl = lane & 15, q = lane >> 4;
    int wm = wave & 1, wn = wave >> 1;
    int m0, n0, zidx, tlin = 0;
    if (TRI) {
        int bid = bx;
        int bxx, tm = 0;
        if (nz == 16) {                 // R7-proven mapping: grid 8*36*2
            int rest = bid >> 3;
            bxx = rest % 36;
            int zhi = rest / 36;
            zidx = (bid & 7) | (zhi << 3);
        } else {                        // fallback: grid 36*4
            zidx = bid & 3;
            bxx = bid >> 2;
        }
        tlin = bxx;
        while (bxx >= 8 - tm) { bxx -= 8 - tm; ++tm; }
        m0 = tm * 128; n0 = (tm + bxx) * 128;
    } else {
        m0 = bx * BM; n0 = by * BN; zidx = bz;
    }
    int lrow8 = lane >> 3, lgrp = lane & 7;
    bool isA = wave < NAW;
    bool active = wave < NAW + NBW;
    int wlocal = isA ? wave : wave - NAW;
    ushort* dstb = ls + (isA ? 0 : BM * 64) + wlocal * 4096;

    f32x4 acc[4][NF];
#pragma unroll
    for (int i = 0; i < 4; ++i)
#pragma unroll
        for (int j = 0; j < NF; ++j) acc[i][j] = f32x4{0.f, 0.f, 0.f, 0.f};

    const ushort* srcb;
    size_t ldS;
    if (isA) {
        srcb = A0 + (size_t)(m0 + wlocal * 64 + lrow8) * lda0 + lgrp * 8;
        ldS = (size_t)lda0;
    } else {
        srcb = B0 + (size_t)(n0 + wlocal * 64 + lrow8) * ldb0 + lgrp * 8;
        ldS = (size_t)ldb0;
    }
    srcb += zidx * k0len;
    for (int kt = 0; kt < k0len; kt += 64) {
        if (active) {
#pragma unroll
            for (int c = 0; c < 8; ++c)
                __builtin_amdgcn_global_load_lds(AS1C(srcb + c * 8 * ldS),
                                                 AS3(dstb + c * 512), 16, 0, 0);
            srcb += 64;
        }
        __syncthreads();
#pragma unroll
        for (int s = 0; s < 2; ++s) {
            bf16x8 af[4], bfr[NF];
#pragma unroll
            for (int i = 0; i < 4; ++i) {
                int row = wm * 64 + i * 16 + rl;
                int sg = ((s << 2) | q) ^ (row & 7);
                af[i] = *(const bf16x8*)&lsA[row * 64 + sg * 8];
            }
#pragma unroll
            for (int j = 0; j < NF; ++j) {
                int row = wn * WTN + j * 16 + rl;
                int sg = ((s << 2) | q) ^ (row & 7);
                bfr[j] = *(const bf16x8*)&lsB[row * 64 + sg * 8];
            }
#pragma unroll
            for (int i = 0; i < 4; ++i)
#pragma unroll
                for (int j = 0; j < NF; ++j)
                    acc[i][j] = __builtin_amdgcn_mfma_f32_16x16x32_bf16(
                        af[i], bfr[j], acc[i][j], 0, 0, 0);
        }
        __syncthreads();
    }

    // plain bf16 pair stores into this z-slice's partial buffer
    ushort* Cb = C + (size_t)zidx * (size_t)pstride;
#pragma unroll
    for (int i = 0; i < 4; ++i)
#pragma unroll
        for (int j = 0; j < NF; ++j)
#pragma unroll
            for (int rg = 0; rg < 4; ++rg) {
                float v = acc[i][j][rg];
                float vp = __shfl_xor(v, 1);   // partner lane's (n^1) value
                if ((rl & 1) == 0) {
                    int ml = wm * 64 + i * 16 + q * 4 + rg;
                    int nl = wn * WTN + j * 16 + rl;
                    size_t off;
                    if (TRI)
                        off = (size_t)tlin * (BM * BN) + (size_t)ml * BN + nl;
                    else
                        off = (size_t)(m0 + ml) * 0 + (size_t)(m0 + ml) * OUTD + nl; // non-TRI: ldc=OUTD
                    unsigned pk = (unsigned)f2bf(v) | ((unsigned)f2bf(vp) << 16);
                    *(unsigned*)(Cb + off) = pk;
                }
            }
}

template<int BM, int BN, int TRI>
__global__ __launch_bounds__(256, 4) void gemm_nt_k(
        const ushort* __restrict__ A0, int lda0,
        const ushort* __restrict__ B0, int ldb0, int k0len,
        ushort* __restrict__ C, int pstride, int nz) {
    __shared__ ushort ls[(BM + BN) * 64];
    gemm0_body<BM, BN, TRI>(A0, lda0, B0, ldb0, k0len, C, pstride, nz,
        blockIdx.x, blockIdx.y, blockIdx.z, ls);
}

// ---------------------------------------------------------------------------
// Fused G-gemm (blocks 0..575, TRI split-K 16) + PtX-gemm (576..831, split-K 32).
__global__ __launch_bounds__(256, 4) void gp_k(const ushort* __restrict__ XnT,
        const ushort* __restrict__ PTb, ushort* __restrict__ Gpart,
        ushort* __restrict__ PXpart) {
    __shared__ ushort ls[256 * 64];
    int bid = blockIdx.x;
    if (bid < 576) {
        gemm0_body<128, 128, 1>(XnT, N_ROWS, XnT, N_ROWS, 1024,
            Gpart, 36 * 16384, 16, bid, 0, 0, ls);
    } else {
        int b2 = bid - 576;
        gemm0_body<128, 64, 0>(XnT, N_ROWS, PTb, N_ROWS, 512,
            PXpart, DIM * OUTD, 0, b2 & 7, 0, b2 >> 3, ls);
    }
}

// ---------------------------------------------------------------------------
// Dedicated update gemm: X_{t+1} = Xn + g*(P@PtX - Xn@G).
// seg0: Xm(ld DIM) @ Gb(ld DIM)^T, K=1024. rvv scale. seg1: Pb @ PtXTb
// (ld OUTD), K=64. Epilogue: vf = base*rinv + gamma*acc -> bf16 master +
// row sum-of-squares atomics. Math order identical to R11's EPI1.
__global__ __launch_bounds__(256, 4) void upd1_k(
        const ushort* __restrict__ Xm, const ushort* __restrict__ Gb,
        const ushort* __restrict__ Pb, const ushort* __restrict__ PtXTb,
        ushort* __restrict__ Cm, const float* __restrict__ ssrd,
        float gamma, float* __restrict__ ssacc) {
    __shared__ ushort ls[256 * 64];
    ushort* lsA = ls;
    ushort* lsB = ls + 128 * 64;
    int t = threadIdx.x;
    int wave = t >> 6, lane = t & 63;
    int rl = lane & 15, q = lane >> 4;
    int wm = wave & 1, wn = wave >> 1;
    int m0 = blockIdx.x * 128, n0 = blockIdx.y * 128;
    int lrow8 = lane >> 3, lgrp = lane & 7;
    bool isA = wave < 2;
    int wlocal = isA ? wave : wave - 2;
    ushort* dstb = ls + (isA ? 0 : 8192) + wlocal * 4096;

    f32x4 acc[4][4];
#pragma unroll
    for (int i = 0; i < 4; ++i)
#pragma unroll
        for (int j = 0; j < 4; ++j) acc[i][j] = f32x4{0.f, 0.f, 0.f, 0.f};

    // seg0: K=1024
    {
        const ushort* srcb = isA
            ? Xm + (size_t)(m0 + wlocal * 64 + lrow8) * DIM + lgrp * 8
            : Gb + (size_t)(n0 + wlocal * 64 + lrow8) * DIM + lgrp * 8;
        for (int kt = 0; kt < 1024; kt += 64) {
#pragma unroll
            for (int c = 0; c < 8; ++c)
                __builtin_amdgcn_global_load_lds(AS1C(srcb + c * 8 * DIM),
                                                 AS3(dstb + c * 512), 16, 0, 0);
            srcb += 64;
            __syncthreads();
#pragma unroll
            for (int s = 0; s < 2; ++s) {
                bf16x8 af[4], bfr[4];
#pragma unroll
                for (int i = 0; i < 4; ++i) {
                    int row = wm * 64 + i * 16 + rl;
                    int sg = ((s << 2) | q) ^ (row & 7);
                    af[i] = *(const bf16x8*)&lsA[row * 64 + sg * 8];
                }
#pragma unroll
                for (int j = 0; j < 4; ++j) {
                    int row = wn * 64 + j * 16 + rl;
                    int sg = ((s << 2) | q) ^ (row & 7);
                    bfr[j] = *(const bf16x8*)&lsB[row * 64 + sg * 8];
                }
#pragma unroll
                for (int i = 0; i < 4; ++i)
#pragma unroll
                    for (int j = 0; j < 4; ++j)
                        acc[i][j] = __builtin_amdgcn_mfma_f32_16x16x32_bf16(
                            af[i], bfr[j], acc[i][j], 0, 0, 0);
            }
            __syncthreads();
        }
    }

    // rvv scale (Xn@G needs rinv[m])
    float rvv[4][4];
#pragma unroll
    for (int i = 0; i < 4; ++i)
#pragma unroll
        for (int rg = 0; rg < 4; ++rg) {
            rvv[i][rg] = 1.0f / sqrtf(ssrd[m0 + wm * 64 + i * 16 + q * 4 + rg]);
#pragma unroll
            for (int j = 0; j < 4; ++j) acc[i][j][rg] *= rvv[i][rg];
        }

    // seg1: K=64
    {
        const ushort* srcb = isA
            ? Pb + (size_t)(m0 + wlocal * 64 + lrow8) * OUTD + lgrp * 8
            : PtXTb + (size_t)(n0 + wlocal * 64 + lrow8) * OUTD + lgrp * 8;
#pragma unroll
        for (int c = 0; c < 8; ++c)
            __builtin_amdgcn_global_load_lds(AS1C(srcb + c * 8 * OUTD),
                                             AS3(dstb + c * 512), 16, 0, 0);
        __syncthreads();
#pragma unroll
        for (int s = 0; s < 2; ++s) {
            bf16x8 af[4], bfr[4];
#pragma unroll
            for (int i = 0; i < 4; ++i) {
                int row = wm * 64 + i * 16 + rl;
                int sg = ((s << 2) | q) ^ (row & 7);
                af[i] = *(const bf16x8*)&lsA[row * 64 + sg * 8];
            }
#pragma unroll
            for (int j = 0; j < 4; ++j) {
                int row = wn * 64 + j * 16 + rl;
                int sg = ((s << 2) | q) ^ (row & 7);
                bfr[j] = *(const bf16x8*)&lsB[row * 64 + sg * 8];
            }
#pragma unroll
            for (int i = 0; i < 4; ++i)
#pragma unroll
                for (int j = 0; j < 4; ++j)
                    acc[i][j] = __builtin_amdgcn_mfma_f32_16x16x32_bf16(
                        af[i], bfr[j], acc[i][j], 0, 0, 0);
        }
    }

    // epilogue: vf = base*rinv + gamma*acc; bf16 master write + ss atomics.
#pragma unroll
    for (int i = 0; i < 4; ++i)
#pragma unroll
        for (int rg = 0; rg < 4; ++rg) {
            int m = m0 + wm * 64 + i * 16 + q * 4 + rg;
            float ssl = 0.f;
#pragma unroll
            for (int j = 0; j < 4; ++j) {
                int n = n0 + wn * 64 + j * 16 + rl;
                int so = swz(n, m);
                float base = b2f(Xm[(size_t)m * DIM + so]);
                float vf = base * rvv[i][rg] + gamma * acc[i][j][rg];
                Cm[(size_t)m * DIM + so] = f2bf(vf);
                ssl += vf * vf;
            }
            ssl += __shfl_xor(ssl, 1);
            ssl += __shfl_xor(ssl, 2);
            ssl += __shfl_xor(ssl, 4);
            ssl += __shfl_xor(ssl, 8);
            if (rl == 0) atomicAdd(&ssacc[m], ssl);
        }
}

// ---------------------------------------------------------------------------
extern "C" void kernel_launch(void* const* d_in, const int* in_sizes, int n_in,
                              void* d_out, int out_size, void* d_ws, size_t ws_size,
                              hipStream_t stream) {
    const float* X = (const float*)d_in[0];
    const float* W1 = (const float*)d_in[1];
    const float* b1 = (const float*)d_in[2];
    const float* W2 = (const float*)d_in[3];
    const float* b2 = (const float*)d_in[4];
    float* out = (float*)d_out;
    char* ws = (char*)d_ws;

    constexpr size_t O_BufA    = 0;                                     // 33,554,432
    constexpr size_t O_BufB    = O_BufA + (size_t)N_ROWS * DIM * 2;     // 33,554,432
    constexpr size_t O_Pb      = O_BufB + (size_t)N_ROWS * DIM * 2;     //  2,097,152
    constexpr size_t O_PTb     = O_Pb + (size_t)N_ROWS * OUTD * 2;      //  2,097,152
    constexpr size_t O_Gb      = O_PTb + (size_t)OUTD * N_ROWS * 2;     //  2,097,152
    constexpr size_t O_PtXTb   = O_Gb + (size_t)DIM * DIM * 2;          //    131,072
    constexpr size_t O_ssB     = O_PtXTb + (size_t)DIM * OUTD * 2;      //     65,536
    constexpr size_t O_W1T     = O_ssB + (size_t)N_ROWS * 4;            //     32,768
    constexpr size_t O_ssA     = O_W1T + (size_t)HID * DIM * 2;         //     65,536
    constexpr size_t O_scratch = O_ssA + (size_t)N_ROWS * 4;            // = 73,695,232
    constexpr size_t WS_BIG = O_scratch + (size_t)16 * 589824 * 2;

    ushort* bufA  = (ushort*)(ws + O_BufA);
    ushort* bufB  = (ushort*)(ws + O_BufB);
    ushort* Pb    = (ushort*)(ws + O_Pb);
    ushort* PTb   = (ushort*)(ws + O_PTb);
    ushort* Gb    = (ushort*)(ws + O_Gb);
    ushort* PtXTb = (ushort*)(ws + O_PtXTb);
    float*  ssB   = (float*)(ws + O_ssB);
    ushort* W1T   = (ushort*)(ws + O_W1T);
    float*  ssA   = (float*)(ws + O_ssA);
    float*  z     = (float*)(ws + O_scratch);
    ushort* Gpart = (ushort*)(ws + O_scratch);
    ushort* PXpart = (ushort*)d_out;
    ushort* Gsum  = PTb;                       // PTb region reuse (dead)
    ushort* PXsum = PTb + 589824;
    (void)in_sizes; (void)n_in; (void)out_size;

    const bool big = ws_size >= WS_BIG;
    const int nzg = big ? 16 : 4;
    const int nzp = big ? 32 : 8;

    prep_w1t_k<<<64, 256, 0, stream>>>(W1, W1T);
    tobf16_k<<<N_ROWS, 256, 0, stream>>>(X, bufA, ssA);

    ushort* xm  = bufA;
    ushort* alt = bufB;
    float* ssCur = ssA;
    float* ssNxt = ssB;

    for (int it = 0; it < DEPTH; ++it) {
        if (big) {
            txz_k<<<4096 + 256, 256, 0, stream>>>(xm, ssCur, alt, W1T, b1, z);
        } else {
            transpose_k<<<dim3(N_ROWS / 64, DIM / 64), 256, 0, stream>>>(xm, ssCur, alt);
            zgemm_k<<<N_ROWS / 64, 256, 0, stream>>>(xm, W1T, b1, z, ssCur);
        }
        head_k<<<N_ROWS / 256, 256, 0, stream>>>(z, W2, b2, Pb, PTb, nullptr, 1);
        if (big) {
            gp_k<<<576 + 256, 256, 0, stream>>>(alt, PTb, Gpart, PXpart);
        } else {
            gemm_nt_k<128, 128, 1><<<dim3(36 * 4, 1, 1), 256, 0, stream>>>(
                alt, N_ROWS, alt, N_ROWS, 4096, Gpart, 36 * 16384, 4);
            gemm_nt_k<128, 64, 0><<<dim3(8, 1, 8), 256, 0, stream>>>(
                alt, N_ROWS, PTb, N_ROWS, 2048, PXpart, DIM * OUTD, 0);
        }
        reduce_k<<<320, 256, 0, stream>>>(Gpart, PXpart, Gsum, PXsum, nzg, nzp);
        castgp_k<<<1088, 256, 0, stream>>>(Gsum, PXsum, Gb, PtXTb, ssNxt);
        // X_{t+1} = Xn + g*(P@PtX - Xn@G); dedicated kernel
        upd1_k<<<dim3(N_ROWS / 128, DIM / 128, 1), 256, 0, stream>>>(
            xm, Gb, Pb, PtXTb, alt, ssCur, GAMMA, ssNxt);
        ushort* tmp = xm; xm = alt; alt = tmp;
        float* ts2 = ssCur; ssCur = ssNxt; ssNxt = ts2;
    }

    zgemm_k<<<N_ROWS / 64, 256, 0, stream>>>(xm, W1T, b1, z, nullptr);
    head_k<<<N_ROWS / 256, 256, 0, stream>>>(z, W2, b2, Pb, PTb, out, 0);
}